// Round 18
// baseline (109.721 us; speedup 1.0000x reference)
//
#include <hip/hip_runtime.h>
#include <hip/hip_bf16.h>

#define BATCH  4
#define SEQ    4096
#define DMODEL 1024
#define HDIM   128
#define MROWS  (BATCH * SEQ)   // 16384
#define NT32   (SEQ / 32)      // 128 q-tiles (32 rows) per batch
#define T32    (BATCH * NT32)  // 512
#define NSMAX  8               // max KV splits (big tiles 8, small tiles 4)

// qkv GEMM tile (round-12/16 proven geometry)
#define BM 64
#define BN 96
#define BK 64
#define KT (DMODEL / BK)       // 16

typedef __attribute__((ext_vector_type(8)))  short short8;
typedef __attribute__((ext_vector_type(4)))  float floatx4;
typedef __attribute__((ext_vector_type(16))) float floatx16;
typedef unsigned int u32;

static __device__ __forceinline__ short f2bf(float f) {
    __hip_bfloat16 h = __float2bfloat16(f);
    union { __hip_bfloat16 h; short s; } u; u.h = h;
    return u.s;
}

static __device__ __forceinline__ float bf2f(unsigned short s) {
    union { u32 u; float f; } v; v.u = ((u32)s) << 16;
    return v.f;
}

static __device__ __forceinline__ short8 ld8(const unsigned short* p) {
    return *reinterpret_cast<const short8*>(p);
}

// async global->LDS, 16 B per lane; LDS dest = wave-uniform base + lane*16.
static __device__ __forceinline__ void gload_lds16(const void* g, void* l) {
    __builtin_amdgcn_global_load_lds(
        (const __attribute__((address_space(1))) unsigned int*)g,
        (__attribute__((address_space(3))) unsigned int*)l,
        16, 0, 0);
}

// pack two f32 -> one u32 of two bf16 (lo = a, hi = b)
static __device__ __forceinline__ u32 cvtpk_bf16(float a, float b) {
    u32 r;
    asm("v_cvt_pk_bf16_f32 %0, %1, %2" : "=v"(r) : "v"(a), "v"(b));
    return r;
}

// a' = {lanes<32: a ; lanes>=32: b from partner(lane-32)}
// b' = {lanes<32: a from partner(lane+32) ; lanes>=32: b}
static __device__ __forceinline__ void swap_halves(u32& a, u32& b) {
#if __has_builtin(__builtin_amdgcn_permlane32_swap)
    typedef __attribute__((ext_vector_type(2))) int int2v;
    int2v r = __builtin_amdgcn_permlane32_swap((int)a, (int)b, false, false);
    a = (u32)r[0]; b = (u32)r[1];
#else
    u32 ap = (u32)__shfl_xor((int)a, 32);
    u32 bp = (u32)__shfl_xor((int)b, 32);
    const bool hih = (threadIdx.x & 32) != 0;
    u32 na = hih ? bp : a;
    u32 nb = hih ? b : ap;
    a = na; b = nb;
#endif
}

// ===========================================================================
// FRAGMENT-TILED LAYOUTS (round-12 proven — attn loads are 1KB coalesced):
//  qt/kt: (b,s,d) at ((b*NT32+s/32)*8 + d/16)*512 + ((d/8)%2*32 + s%32)*8 + d%8
//  vtl:   (b,s,d) at ((b*NT32+s/32)*8 + (d/32)*2 + (s%32)/16)*512
//                     + ((s/8)%2*32 + d%32)*8 + s%8
// ===========================================================================

// ---------------------------------------------------------------------------
// W = [Wq;Wk;Wv] fp32 -> bf16, Wq pre-scaled by 1/sqrt(H). One launch.
// ---------------------------------------------------------------------------
__global__ __launch_bounds__(256) void cvt_w_kernel(
    const float* __restrict__ Wq, const float* __restrict__ Wk,
    const float* __restrict__ Wv, unsigned short* __restrict__ wbf)
{
    const int n8w = HDIM * DMODEL / 8;                // 16384
    int i = blockIdx.x * 256 + threadIdx.x;
    if (i >= 3 * n8w) return;
    const int which = i / n8w;
    const int j = i - which * n8w;
    const float* src = (which == 0) ? Wq : (which == 1) ? Wk : Wv;
    const float scale = (which == 0) ? 0.08838834764831845f : 1.0f;
    const float4* s4 = reinterpret_cast<const float4*>(src);
    float4 a = s4[2 * j];
    float4 b = s4[2 * j + 1];
    short8 o;
    o[0] = f2bf(a.x * scale); o[1] = f2bf(a.y * scale);
    o[2] = f2bf(a.z * scale); o[3] = f2bf(a.w * scale);
    o[4] = f2bf(b.x * scale); o[5] = f2bf(b.y * scale);
    o[6] = f2bf(b.z * scale); o[7] = f2bf(b.w * scale);
    reinterpret_cast<short8*>(wbf)[i] = o;
}

// ---------------------------------------------------------------------------
// QKV projection, double-buffered LDS GEMM (round-16 proven, unchanged).
// ---------------------------------------------------------------------------
__global__ __launch_bounds__(256, 4) void qkv_kernel(
    const float* __restrict__ x,             // [MROWS][DMODEL] fp32
    const unsigned short* __restrict__ wbf,  // [384][DMODEL] bf16
    unsigned short* __restrict__ qt,         // tiled Q
    unsigned short* __restrict__ kt,         // tiled K
    unsigned short* __restrict__ vtl)        // tiled V
{
    __shared__ __align__(16) unsigned short A_lds[2][BM][BK];  // 16 KB
    __shared__ __align__(16) unsigned short B_lds[2][BN][BK];  // 24 KB

    const int raw  = blockIdx.x;
    const int vid  = (raw & 7) * 128 + (raw >> 3);
    const int mblk = vid >> 2;
    const int nblk = vid & 3;
    const int m0   = mblk * BM;
    const int n0   = nblk * BN;

    const int tid  = threadIdx.x;
    const int wv   = tid >> 6;
    const int lane = tid & 63;
    const int lr   = lane & 15;
    const int lh   = lane >> 4;
    const int wm   = wv >> 1;   // 0/1 -> M offset 0/32
    const int wn   = wv & 1;    // 0/1 -> N offset 0/48

    const int ar = tid >> 2;
    const int aq = tid & 3;
    const float* asrc = x + (size_t)(m0 + ar) * DMODEL + aq * 16;

    const int brow  = lane >> 3;
    const int bunit = (lane & 7) ^ brow;

    floatx4 acc[2][3];
#pragma unroll
    for (int mf = 0; mf < 2; ++mf)
#pragma unroll
        for (int nf = 0; nf < 3; ++nf) acc[mf][nf] = (floatx4){0.f, 0.f, 0.f, 0.f};

    // ---- prologue: stage tile 0 into buffer 0 ----
    {
#pragma unroll
        for (int j = 0; j < 3; ++j) {
            const int rbase = (j * 4 + wv) * 8;
            gload_lds16(wbf + (size_t)(n0 + rbase + brow) * DMODEL + bunit * 8,
                        &B_lds[0][rbase][0]);
        }
        float4 f0 = *reinterpret_cast<const float4*>(asrc);
        float4 f1 = *reinterpret_cast<const float4*>(asrc + 4);
        float4 f2 = *reinterpret_cast<const float4*>(asrc + 8);
        float4 f3 = *reinterpret_cast<const float4*>(asrc + 12);
        short8 v0, v1;
        v0[0] = f2bf(f0.x); v0[1] = f2bf(f0.y); v0[2] = f2bf(f0.z); v0[3] = f2bf(f0.w);
        v0[4] = f2bf(f1.x); v0[5] = f2bf(f1.y); v0[6] = f2bf(f1.z); v0[7] = f2bf(f1.w);
        v1[0] = f2bf(f2.x); v1[1] = f2bf(f2.y); v1[2] = f2bf(f2.z); v1[3] = f2bf(f2.w);
        v1[4] = f2bf(f3.x); v1[5] = f2bf(f3.y); v1[6] = f2bf(f3.z); v1[7] = f2bf(f3.w);
        const int u0 = (2 * aq)     ^ (ar & 7);
        const int u1 = (2 * aq + 1) ^ (ar & 7);
        *reinterpret_cast<short8*>(&A_lds[0][ar][u0 * 8]) = v0;
        *reinterpret_cast<short8*>(&A_lds[0][ar][u1 * 8]) = v1;
    }
    __syncthreads();

    for (int ktile = 0; ktile < KT; ++ktile) {
        const int cur = ktile & 1;
        const int nxt = cur ^ 1;
        float4 f0, f1, f2, f3;
        if (ktile + 1 < KT) {
#pragma unroll
            for (int j = 0; j < 3; ++j) {
                const int rbase = (j * 4 + wv) * 8;
                gload_lds16(wbf + (size_t)(n0 + rbase + brow) * DMODEL
                                + (ktile + 1) * BK + bunit * 8,
                            &B_lds[nxt][rbase][0]);
            }
            const float* a = asrc + (ktile + 1) * BK;
            f0 = *reinterpret_cast<const float4*>(a);
            f1 = *reinterpret_cast<const float4*>(a + 4);
            f2 = *reinterpret_cast<const float4*>(a + 8);
            f3 = *reinterpret_cast<const float4*>(a + 12);
        }
#pragma unroll
        for (int kk = 0; kk < 2; ++kk) {
            const int uswz = (kk * 4 + lh) ^ (lr & 7);
            short8 af[2], bfr[3];
#pragma unroll
            for (int mf = 0; mf < 2; ++mf)
                af[mf] = ld8(&A_lds[cur][wm * 32 + mf * 16 + lr][uswz * 8]);
#pragma unroll
            for (int nf = 0; nf < 3; ++nf)
                bfr[nf] = ld8(&B_lds[cur][wn * 48 + nf * 16 + lr][uswz * 8]);
#pragma unroll
            for (int mf = 0; mf < 2; ++mf)
#pragma unroll
                for (int nf = 0; nf < 3; ++nf)
                    acc[mf][nf] = __builtin_amdgcn_mfma_f32_16x16x32_bf16(
                        af[mf], bfr[nf], acc[mf][nf], 0, 0, 0);
        }
        if (ktile + 1 < KT) {
            short8 v0, v1;
            v0[0] = f2bf(f0.x); v0[1] = f2bf(f0.y); v0[2] = f2bf(f0.z); v0[3] = f2bf(f0.w);
            v0[4] = f2bf(f1.x); v0[5] = f2bf(f1.y); v0[6] = f2bf(f1.z); v0[7] = f2bf(f1.w);
            v1[0] = f2bf(f2.x); v1[1] = f2bf(f2.y); v1[2] = f2bf(f2.z); v1[3] = f2bf(f2.w);
            v1[4] = f2bf(f3.x); v1[5] = f2bf(f3.y); v1[6] = f2bf(f3.z); v1[7] = f2bf(f3.w);
            const int u0 = (2 * aq)     ^ (ar & 7);
            const int u1 = (2 * aq + 1) ^ (ar & 7);
            *reinterpret_cast<short8*>(&A_lds[nxt][ar][u0 * 8]) = v0;
            *reinterpret_cast<short8*>(&A_lds[nxt][ar][u1 * 8]) = v1;
        }
        __syncthreads();
    }

    // ======== epilogue: LDS-staged, coalesced copy-out (round-16 proven) ====
    __syncthreads();
    unsigned short* out_l = &A_lds[0][0][0];   // 12KB image

    const int t0 = (m0 & (SEQ - 1)) >> 5;
    const int bb = m0 >> 12;
    const int st = wm;

#pragma unroll
    for (int nf = 0; nf < 3; ++nf) {
        const int cl = wn * 48 + nf * 16 + lr;
#pragma unroll
        for (int mf = 0; mf < 2; ++mf) {
#pragma unroll
            for (int r = 0; r < 4; ++r) {
                const int srow = mf * 16 + lh * 4 + r;
                const unsigned short vv = (unsigned short)f2bf(acc[mf][nf][r]);
                int lf, off;
                if (nblk == 0) {
                    lf  = st * 6 + (cl >> 4);
                    off = ((cl >> 3) & 1) * 256 + srow * 8 + (cl & 7);
                } else if (nblk == 1) {
                    lf  = (cl < 32) ? st * 6 + (cl >> 4)
                                    : st * 6 + 2 + ((cl - 32) >> 4);
                    off = ((cl >> 3) & 1) * 256 + srow * 8 + (cl & 7);
                } else if (nblk == 2) {
                    if (cl < 64) {
                        lf  = st * 6 + (cl >> 4);
                        off = ((cl >> 3) & 1) * 256 + srow * 8 + (cl & 7);
                    } else {
                        const int dg = cl - 64;
                        lf  = st * 6 + 4 + ((srow >> 4) & 1);
                        off = ((srow >> 3) & 1) * 256 + dg * 8 + (srow & 7);
                    }
                } else {
                    const int d = cl + 32;
                    lf  = st * 6 + ((d >> 5) - 1) * 2 + ((srow >> 4) & 1);
                    off = ((srow >> 3) & 1) * 256 + (d & 31) * 8 + (srow & 7);
                }
                out_l[lf * 512 + off] = vv;
            }
        }
    }
    __syncthreads();

#pragma unroll
    for (int k = 0; k < 3; ++k) {
        const int u   = tid + 256 * k;
        const int fb  = u >> 6;
        const int iu  = u & 63;
        const int fst = (fb >= 6) ? 1 : 0;
        const int li  = fb - 6 * fst;
        const size_t tb8 = (size_t)((bb * NT32 + t0 + fst) * 8);
        unsigned short* gbase;
        if (nblk == 0) {
            gbase = qt + ((tb8 + li) << 9);
        } else if (nblk == 1) {
            gbase = (li < 2) ? qt  + ((tb8 + 6 + li) << 9)
                             : kt  + ((tb8 + (li - 2)) << 9);
        } else if (nblk == 2) {
            gbase = (li < 4) ? kt  + ((tb8 + 4 + li) << 9)
                             : vtl + ((tb8 + (li - 4)) << 9);
        } else {
            gbase = vtl + ((tb8 + 2 + li) << 9);
        }
        *reinterpret_cast<short8*>(gbase + iu * 8) =
            *reinterpret_cast<const short8*>(&out_l[fb * 512 + iu * 8]);
    }
}

// ---------------------------------------------------------------------------
// Causal flash attention — round-12 proven structure; ADAPTIVE split count:
// big tiles (t32b >= 64, nkv 2080..4096) -> 8 splits, small tiles -> 4.
// Every block <= 16 iterations (NS=4's 32-iter tail was the wall clock).
// Grid 3072 = 8 XCD * (32 big * 8 + 32 small * 4); XCD-pinned, longest-first.
// ---------------------------------------------------------------------------
__global__ __launch_bounds__(64) void attn_kernel(
    const unsigned short* __restrict__ qt,
    const unsigned short* __restrict__ kt,
    const unsigned short* __restrict__ vtl,
    unsigned short* __restrict__ pacc,   // [NSMAX][T32][128][32] bf16
    float* __restrict__ pm,
    float* __restrict__ pl)
{
    const int bid  = blockIdx.x;
    const int xcd  = bid & 7;
    const int b    = xcd >> 1;                // batch <-> XCD pair
    const int par  = xcd & 1;
    const int idx  = bid >> 3;                // 0..383 within XCD
    int s, t32b, ns;
    if (idx < 256) {                          // big tiles: 8 splits
        ns   = 8;
        s    = idx & 7;
        t32b = 127 - 2 * (idx >> 3) - par;    // 64..127
    } else {                                  // small tiles: 4 splits
        ns   = 4;
        const int j = idx - 256;
        s    = j & 3;
        t32b = 63 - 2 * (j >> 2) - par;       // 0..63
    }
    const int q0   = t32b * 32;
    const int t32  = b * NT32 + t32b;
    const int lane = threadIdx.x & 63;
    const int l31  = lane & 31;
    const int hih  = lane >> 5;

    const int nkv   = q0 + 32;
    const int chunk = ((nkv + ns * 32 - 1) / (ns * 32)) * 32;
    const int lo    = s * chunk;
    const int hikv  = (lo + chunk < nkv) ? lo + chunk : nkv;
    const size_t mlbase = (size_t)(s * T32 + t32) * 32;

    if (lo >= hikv) {
        if (lane < 32) { pm[mlbase + l31] = -3.0e38f; pl[mlbase + l31] = 0.f; }
        return;
    }

    // Q fragments (coalesced tiled loads)
    const unsigned short* qtb =
        qt + ((size_t)((b * NT32 + t32b) * 8) << 9) + lane * 8;
    short8 qa[8];
#pragma unroll
    for (int ks = 0; ks < 8; ++ks) qa[ks] = ld8(qtb + (ks << 9));

    floatx16 acco[4];
#pragma unroll
    for (int db = 0; db < 4; ++db)
#pragma unroll
        for (int i = 0; i < 16; ++i) acco[db][i] = 0.f;
    float m_r = -3.0e38f, l_r = 0.f;

    for (int kv0 = lo; kv0 < hikv; kv0 += 32) {
        const int t = kv0 >> 5;
        const unsigned short* ktb =
            kt + ((size_t)((b * NT32 + t) * 8) << 9) + lane * 8;
        const unsigned short* vtb =
            vtl + ((size_t)((b * NT32 + t) * 8) << 9) + lane * 8;

        // ---- scores S^T[kv][q] = mfma(K, Q) ----
        floatx16 sc;
#pragma unroll
        for (int i = 0; i < 16; ++i) sc[i] = 0.f;
#pragma unroll
        for (int ks = 0; ks < 8; ++ks) {
            short8 kf = ld8(ktb + (ks << 9));
            sc = __builtin_amdgcn_mfma_f32_32x32x16_bf16(kf, qa[ks], sc, 0, 0, 0);
        }
        // ---- causal mask: only the diagonal tile ----
        if (kv0 == q0) {
#pragma unroll
            for (int r = 0; r < 16; ++r) {
                const int kvloc = (r & 3) + 8 * (r >> 2) + 4 * hih;
                if (kvloc > l31) sc[r] = -3.0e38f;
            }
        }
        // ---- lane-local max (tree) + cross-half ----
        float t8[8];
#pragma unroll
        for (int i = 0; i < 8; ++i) t8[i] = fmaxf(sc[i], sc[i + 8]);
        float t4a = fmaxf(t8[0], t8[4]), t4b = fmaxf(t8[1], t8[5]);
        float t4c = fmaxf(t8[2], t8[6]), t4d = fmaxf(t8[3], t8[7]);
        float pmax = fmaxf(fmaxf(t4a, t4b), fmaxf(t4c, t4d));
        pmax = fmaxf(pmax, __shfl_xor(pmax, 32));
        // ---- deferred rescale (T13, THR=8) ----
        if (__any(pmax > m_r + 8.f)) {
            const float mn  = fmaxf(m_r, pmax);
            const float fac = __expf(m_r - mn);
            m_r = mn; l_r *= fac;
#pragma unroll
            for (int db = 0; db < 4; ++db)
#pragma unroll
                for (int i = 0; i < 16; ++i) acco[db][i] *= fac;
        }
        // ---- p = exp(s - m), lane-local sum ----
        float p[16];
#pragma unroll
        for (int r = 0; r < 16; ++r) p[r] = __expf(sc[r] - m_r);
        float s8[8];
#pragma unroll
        for (int i = 0; i < 8; ++i) s8[i] = p[i] + p[i + 8];
        float s4a = s8[0] + s8[4], s4b = s8[1] + s8[5];
        float s4c = s8[2] + s8[6], s4d = s8[3] + s8[7];
        float ps = (s4a + s4b) + (s4c + s4d);
        ps += __shfl_xor(ps, 32);
        l_r += ps;
        // ---- pack P^T B-fragments (T12: cvt_pk + permlane32_swap) ----
        u32 pk0 = cvtpk_bf16(p[0], p[1]),   pk2 = cvtpk_bf16(p[4], p[5]);
        swap_halves(pk0, pk2);
        u32 pk1 = cvtpk_bf16(p[2], p[3]),   pk3 = cvtpk_bf16(p[6], p[7]);
        swap_halves(pk1, pk3);
        u32 pk4 = cvtpk_bf16(p[8], p[9]),   pk6 = cvtpk_bf16(p[12], p[13]);
        swap_halves(pk4, pk6);
        u32 pk5 = cvtpk_bf16(p[10], p[11]), pk7 = cvtpk_bf16(p[14], p[15]);
        swap_halves(pk5, pk7);
        union { u32 u[4]; short8 s8v; } ua, ub;
        ua.u[0] = pk0; ua.u[1] = pk1; ua.u[2] = pk2; ua.u[3] = pk3;
        ub.u[0] = pk4; ub.u[1] = pk5; ub.u[2] = pk6; ub.u[3] = pk7;
        const short8 pa0 = ua.s8v, pa1 = ub.s8v;
        // ---- PV: O^T[d][q] += V^T x P^T (coalesced tiled V loads) ----
#pragma unroll
        for (int db = 0; db < 4; ++db) {
            short8 vf0 = ld8(vtb + ((db * 2)     << 9));
            acco[db] = __builtin_amdgcn_mfma_f32_32x32x16_bf16(vf0, pa0, acco[db], 0, 0, 0);
            short8 vf1 = ld8(vtb + ((db * 2 + 1) << 9));
            acco[db] = __builtin_amdgcn_mfma_f32_32x32x16_bf16(vf1, pa1, acco[db], 0, 0, 0);
        }
    }

    // ---- write partials (bf16, transposed, coalesced over q) ----
    unsigned short* pt = pacc + (size_t)(s * T32 + t32) * 128 * 32;
#pragma unroll
    for (int db = 0; db < 4; ++db)
#pragma unroll
        for (int r = 0; r < 16; ++r) {
            const int dloc = db * 32 + (r & 3) + 8 * (r >> 2) + 4 * hih;
            pt[(size_t)dloc * 32 + l31] = (unsigned short)f2bf(acco[db][r]);
        }
    if (lane < 32) { pm[mlbase + l31] = m_r; pl[mlbase + l31] = l_r; }
}

// ---------------------------------------------------------------------------
// Combine ns partials per 32-row tile (ns = 8 for big tiles, 4 for small);
// LDS transpose for coalesced output.
// ---------------------------------------------------------------------------
__global__ __launch_bounds__(256) void combine_kernel(
    const unsigned short* __restrict__ pacc, const float* __restrict__ pm,
    const float* __restrict__ pl, float* __restrict__ out)
{
    __shared__ float wlds[NSMAX][32];
    __shared__ float tlds[128][33];
    const int t32  = blockIdx.x;
    const int tid  = threadIdx.x;
    const int t32b = t32 & (NT32 - 1);
    const int ns   = (t32b >= 64) ? 8 : 4;

    if (tid < 32) {
        const int q = tid;
        float ms[NSMAX], ls[NSMAX];
        float M = -3.0e38f;
        for (int s = 0; s < ns; ++s) {
            ms[s] = pm[(size_t)(s * T32 + t32) * 32 + q];
            ls[s] = pl[(size_t)(s * T32 + t32) * 32 + q];
            M = fmaxf(M, ms[s]);
        }
        float den = 0.f;
        for (int s = 0; s < ns; ++s) {
            const float w = __expf(ms[s] - M);
            den += w * ls[s];
            wlds[s][q] = w;
        }
        const float inv = 1.f / den;
        for (int s = 0; s < ns; ++s) wlds[s][q] *= inv;
    }
    __syncthreads();

#pragma unroll
    for (int rep = 0; rep < 16; ++rep) {
        const int flat = rep * 256 + tid;
        const int d = flat >> 5, q = flat & 31;
        float acc = 0.f;
        for (int s = 0; s < ns; ++s)
            acc += wlds[s][q] *
                   bf2f(pacc[((size_t)(s * T32 + t32) * 128 + d) * 32 + q]);
        tlds[d][q] = acc;
    }
    __syncthreads();

    const size_t row0 = (size_t)t32 * 32;
#pragma unroll
    for (int rep = 0; rep < 16; ++rep) {
        const int flat = rep * 256 + tid;
        const int q = flat >> 7, d = flat & 127;
        out[(row0 + q) * 128 + d] = tlds[d][q];
    }
}

// ---------------------------------------------------------------------------
extern "C" void kernel_launch(void* const* d_in, const int* in_sizes, int n_in,
                              void* d_out, int out_size, void* d_ws, size_t ws_size,
                              hipStream_t stream)
{
    const float* x  = (const float*)d_in[0];
    const float* Wq = (const float*)d_in[1];
    const float* Wk = (const float*)d_in[2];
    const float* Wv = (const float*)d_in[3];
    float* out = (float*)d_out;

    const size_t TBUF = (size_t)BATCH * NT32 * 8 * 512;           // 2M shorts = 4MB

    unsigned short* wbf  = (unsigned short*)d_ws;                 // 384*1024 bf16
    unsigned short* qt   = wbf + (size_t)384 * DMODEL;
    unsigned short* ktb  = qt + TBUF;
    unsigned short* vtl  = ktb + TBUF;
    unsigned short* pacc = vtl + TBUF;                            // 8*512*128*32 bf16 = 32MB
    float* pm = (float*)(pacc + (size_t)NSMAX * T32 * 128 * 32);
    float* pl = pm + (size_t)NSMAX * T32 * 32;
    // total ~45.3 MB (round-16 proven footprint)

    const int n8w3 = 3 * HDIM * DMODEL / 8;
    cvt_w_kernel<<<(n8w3 + 255) / 256, 256, 0, stream>>>(Wq, Wk, Wv, wbf);

    qkv_kernel<<<(MROWS / BM) * (384 / BN), 256, 0, stream>>>(x, wbf, qt, ktb, vtl);

    // grid: 8 XCDs * (32 big-tiles * 8 splits + 32 small-tiles * 4 splits) = 3072
    attn_kernel<<<8 * (32 * 8 + 32 * 4), 64, 0, stream>>>(qt, ktb, vtl, pacc, pm, pl);

    combine_kernel<<<T32, 256, 0, stream>>>(pacc, pm, pl, out);
}

// Round 19
// 86.940 us; speedup vs baseline: 1.2620x; 1.2620x over previous
//
#include <hip/hip_runtime.h>
#include <hip/hip_bf16.h>

#define BATCH  4
#define SEQ    4096
#define DMODEL 1024
#define HDIM   128
#define MROWS  (BATCH * SEQ)   // 16384
#define NT32   (SEQ / 32)      // 128 q-tiles (32 rows) per batch
#define T32    (BATCH * NT32)  // 512
#define NS     4               // KV splits per q-tile (bf16 partials)

// qkv GEMM tile (round-12/16 proven geometry)
#define BM 64
#define BN 96
#define BK 64
#define KT (DMODEL / BK)       // 16

typedef __attribute__((ext_vector_type(8)))  short short8;
typedef __attribute__((ext_vector_type(4)))  float floatx4;
typedef __attribute__((ext_vector_type(16))) float floatx16;
typedef unsigned int u32;

static __device__ __forceinline__ short f2bf(float f) {
    __hip_bfloat16 h = __float2bfloat16(f);
    union { __hip_bfloat16 h; short s; } u; u.h = h;
    return u.s;
}

static __device__ __forceinline__ float bf2f(unsigned short s) {
    union { u32 u; float f; } v; v.u = ((u32)s) << 16;
    return v.f;
}

static __device__ __forceinline__ short8 ld8(const unsigned short* p) {
    return *reinterpret_cast<const short8*>(p);
}

// async global->LDS, 16 B per lane; LDS dest = wave-uniform base + lane*16.
static __device__ __forceinline__ void gload_lds16(const void* g, void* l) {
    __builtin_amdgcn_global_load_lds(
        (const __attribute__((address_space(1))) unsigned int*)g,
        (__attribute__((address_space(3))) unsigned int*)l,
        16, 0, 0);
}

// pack two f32 -> one u32 of two bf16 (lo = a, hi = b)
static __device__ __forceinline__ u32 cvtpk_bf16(float a, float b) {
    u32 r;
    asm("v_cvt_pk_bf16_f32 %0, %1, %2" : "=v"(r) : "v"(a), "v"(b));
    return r;
}

// a' = {lanes<32: a ; lanes>=32: b from partner(lane-32)}
// b' = {lanes<32: a from partner(lane+32) ; lanes>=32: b}
static __device__ __forceinline__ void swap_halves(u32& a, u32& b) {
#if __has_builtin(__builtin_amdgcn_permlane32_swap)
    typedef __attribute__((ext_vector_type(2))) int int2v;
    int2v r = __builtin_amdgcn_permlane32_swap((int)a, (int)b, false, false);
    a = (u32)r[0]; b = (u32)r[1];
#else
    u32 ap = (u32)__shfl_xor((int)a, 32);
    u32 bp = (u32)__shfl_xor((int)b, 32);
    const bool hih = (threadIdx.x & 32) != 0;
    u32 na = hih ? bp : a;
    u32 nb = hih ? b : ap;
    a = na; b = nb;
#endif
}

// ===========================================================================
// FRAGMENT-TILED LAYOUTS (round-12 proven — attn loads are 1KB coalesced):
//  qt/kt: (b,s,d) at ((b*NT32+s/32)*8 + d/16)*512 + ((d/8)%2*32 + s%32)*8 + d%8
//  vtl:   (b,s,d) at ((b*NT32+s/32)*8 + (d/32)*2 + (s%32)/16)*512
//                     + ((s/8)%2*32 + d%32)*8 + s%8
// ===========================================================================

// ---------------------------------------------------------------------------
// W = [Wq;Wk;Wv] fp32 -> bf16, Wq pre-scaled by 1/sqrt(H). One launch.
// ---------------------------------------------------------------------------
__global__ __launch_bounds__(256) void cvt_w_kernel(
    const float* __restrict__ Wq, const float* __restrict__ Wk,
    const float* __restrict__ Wv, unsigned short* __restrict__ wbf)
{
    const int n8w = HDIM * DMODEL / 8;                // 16384
    int i = blockIdx.x * 256 + threadIdx.x;
    if (i >= 3 * n8w) return;
    const int which = i / n8w;
    const int j = i - which * n8w;
    const float* src = (which == 0) ? Wq : (which == 1) ? Wk : Wv;
    const float scale = (which == 0) ? 0.08838834764831845f : 1.0f;
    const float4* s4 = reinterpret_cast<const float4*>(src);
    float4 a = s4[2 * j];
    float4 b = s4[2 * j + 1];
    short8 o;
    o[0] = f2bf(a.x * scale); o[1] = f2bf(a.y * scale);
    o[2] = f2bf(a.z * scale); o[3] = f2bf(a.w * scale);
    o[4] = f2bf(b.x * scale); o[5] = f2bf(b.y * scale);
    o[6] = f2bf(b.z * scale); o[7] = f2bf(b.w * scale);
    reinterpret_cast<short8*>(wbf)[i] = o;
}

// ---------------------------------------------------------------------------
// QKV projection, double-buffered LDS GEMM (round-16 proven, unchanged).
// ---------------------------------------------------------------------------
__global__ __launch_bounds__(256, 4) void qkv_kernel(
    const float* __restrict__ x,             // [MROWS][DMODEL] fp32
    const unsigned short* __restrict__ wbf,  // [384][DMODEL] bf16
    unsigned short* __restrict__ qt,         // tiled Q
    unsigned short* __restrict__ kt,         // tiled K
    unsigned short* __restrict__ vtl)        // tiled V
{
    __shared__ __align__(16) unsigned short A_lds[2][BM][BK];  // 16 KB
    __shared__ __align__(16) unsigned short B_lds[2][BN][BK];  // 24 KB

    const int raw  = blockIdx.x;
    const int vid  = (raw & 7) * 128 + (raw >> 3);
    const int mblk = vid >> 2;
    const int nblk = vid & 3;
    const int m0   = mblk * BM;
    const int n0   = nblk * BN;

    const int tid  = threadIdx.x;
    const int wv   = tid >> 6;
    const int lane = tid & 63;
    const int lr   = lane & 15;
    const int lh   = lane >> 4;
    const int wm   = wv >> 1;   // 0/1 -> M offset 0/32
    const int wn   = wv & 1;    // 0/1 -> N offset 0/48

    const int ar = tid >> 2;
    const int aq = tid & 3;
    const float* asrc = x + (size_t)(m0 + ar) * DMODEL + aq * 16;

    const int brow  = lane >> 3;
    const int bunit = (lane & 7) ^ brow;

    floatx4 acc[2][3];
#pragma unroll
    for (int mf = 0; mf < 2; ++mf)
#pragma unroll
        for (int nf = 0; nf < 3; ++nf) acc[mf][nf] = (floatx4){0.f, 0.f, 0.f, 0.f};

    // ---- prologue: stage tile 0 into buffer 0 ----
    {
#pragma unroll
        for (int j = 0; j < 3; ++j) {
            const int rbase = (j * 4 + wv) * 8;
            gload_lds16(wbf + (size_t)(n0 + rbase + brow) * DMODEL + bunit * 8,
                        &B_lds[0][rbase][0]);
        }
        float4 f0 = *reinterpret_cast<const float4*>(asrc);
        float4 f1 = *reinterpret_cast<const float4*>(asrc + 4);
        float4 f2 = *reinterpret_cast<const float4*>(asrc + 8);
        float4 f3 = *reinterpret_cast<const float4*>(asrc + 12);
        short8 v0, v1;
        v0[0] = f2bf(f0.x); v0[1] = f2bf(f0.y); v0[2] = f2bf(f0.z); v0[3] = f2bf(f0.w);
        v0[4] = f2bf(f1.x); v0[5] = f2bf(f1.y); v0[6] = f2bf(f1.z); v0[7] = f2bf(f1.w);
        v1[0] = f2bf(f2.x); v1[1] = f2bf(f2.y); v1[2] = f2bf(f2.z); v1[3] = f2bf(f2.w);
        v1[4] = f2bf(f3.x); v1[5] = f2bf(f3.y); v1[6] = f2bf(f3.z); v1[7] = f2bf(f3.w);
        const int u0 = (2 * aq)     ^ (ar & 7);
        const int u1 = (2 * aq + 1) ^ (ar & 7);
        *reinterpret_cast<short8*>(&A_lds[0][ar][u0 * 8]) = v0;
        *reinterpret_cast<short8*>(&A_lds[0][ar][u1 * 8]) = v1;
    }
    __syncthreads();

    for (int ktile = 0; ktile < KT; ++ktile) {
        const int cur = ktile & 1;
        const int nxt = cur ^ 1;
        float4 f0, f1, f2, f3;
        if (ktile + 1 < KT) {
#pragma unroll
            for (int j = 0; j < 3; ++j) {
                const int rbase = (j * 4 + wv) * 8;
                gload_lds16(wbf + (size_t)(n0 + rbase + brow) * DMODEL
                                + (ktile + 1) * BK + bunit * 8,
                            &B_lds[nxt][rbase][0]);
            }
            const float* a = asrc + (ktile + 1) * BK;
            f0 = *reinterpret_cast<const float4*>(a);
            f1 = *reinterpret_cast<const float4*>(a + 4);
            f2 = *reinterpret_cast<const float4*>(a + 8);
            f3 = *reinterpret_cast<const float4*>(a + 12);
        }
#pragma unroll
        for (int kk = 0; kk < 2; ++kk) {
            const int uswz = (kk * 4 + lh) ^ (lr & 7);
            short8 af[2], bfr[3];
#pragma unroll
            for (int mf = 0; mf < 2; ++mf)
                af[mf] = ld8(&A_lds[cur][wm * 32 + mf * 16 + lr][uswz * 8]);
#pragma unroll
            for (int nf = 0; nf < 3; ++nf)
                bfr[nf] = ld8(&B_lds[cur][wn * 48 + nf * 16 + lr][uswz * 8]);
#pragma unroll
            for (int mf = 0; mf < 2; ++mf)
#pragma unroll
                for (int nf = 0; nf < 3; ++nf)
                    acc[mf][nf] = __builtin_amdgcn_mfma_f32_16x16x32_bf16(
                        af[mf], bfr[nf], acc[mf][nf], 0, 0, 0);
        }
        if (ktile + 1 < KT) {
            short8 v0, v1;
            v0[0] = f2bf(f0.x); v0[1] = f2bf(f0.y); v0[2] = f2bf(f0.z); v0[3] = f2bf(f0.w);
            v0[4] = f2bf(f1.x); v0[5] = f2bf(f1.y); v0[6] = f2bf(f1.z); v0[7] = f2bf(f1.w);
            v1[0] = f2bf(f2.x); v1[1] = f2bf(f2.y); v1[2] = f2bf(f2.z); v1[3] = f2bf(f2.w);
            v1[4] = f2bf(f3.x); v1[5] = f2bf(f3.y); v1[6] = f2bf(f3.z); v1[7] = f2bf(f3.w);
            const int u0 = (2 * aq)     ^ (ar & 7);
            const int u1 = (2 * aq + 1) ^ (ar & 7);
            *reinterpret_cast<short8*>(&A_lds[nxt][ar][u0 * 8]) = v0;
            *reinterpret_cast<short8*>(&A_lds[nxt][ar][u1 * 8]) = v1;
        }
        __syncthreads();
    }

    // ======== epilogue: LDS-staged, coalesced copy-out (round-16 proven) ====
    __syncthreads();
    unsigned short* out_l = &A_lds[0][0][0];   // 12KB image

    const int t0 = (m0 & (SEQ - 1)) >> 5;
    const int bb = m0 >> 12;
    const int st = wm;

#pragma unroll
    for (int nf = 0; nf < 3; ++nf) {
        const int cl = wn * 48 + nf * 16 + lr;
#pragma unroll
        for (int mf = 0; mf < 2; ++mf) {
#pragma unroll
            for (int r = 0; r < 4; ++r) {
                const int srow = mf * 16 + lh * 4 + r;
                const unsigned short vv = (unsigned short)f2bf(acc[mf][nf][r]);
                int lf, off;
                if (nblk == 0) {
                    lf  = st * 6 + (cl >> 4);
                    off = ((cl >> 3) & 1) * 256 + srow * 8 + (cl & 7);
                } else if (nblk == 1) {
                    lf  = (cl < 32) ? st * 6 + (cl >> 4)
                                    : st * 6 + 2 + ((cl - 32) >> 4);
                    off = ((cl >> 3) & 1) * 256 + srow * 8 + (cl & 7);
                } else if (nblk == 2) {
                    if (cl < 64) {
                        lf  = st * 6 + (cl >> 4);
                        off = ((cl >> 3) & 1) * 256 + srow * 8 + (cl & 7);
                    } else {
                        const int dg = cl - 64;
                        lf  = st * 6 + 4 + ((srow >> 4) & 1);
                        off = ((srow >> 3) & 1) * 256 + dg * 8 + (srow & 7);
                    }
                } else {
                    const int d = cl + 32;
                    lf  = st * 6 + ((d >> 5) - 1) * 2 + ((srow >> 4) & 1);
                    off = ((srow >> 3) & 1) * 256 + (d & 31) * 8 + (srow & 7);
                }
                out_l[lf * 512 + off] = vv;
            }
        }
    }
    __syncthreads();

#pragma unroll
    for (int k = 0; k < 3; ++k) {
        const int u   = tid + 256 * k;
        const int fb  = u >> 6;
        const int iu  = u & 63;
        const int fst = (fb >= 6) ? 1 : 0;
        const int li  = fb - 6 * fst;
        const size_t tb8 = (size_t)((bb * NT32 + t0 + fst) * 8);
        unsigned short* gbase;
        if (nblk == 0) {
            gbase = qt + ((tb8 + li) << 9);
        } else if (nblk == 1) {
            gbase = (li < 2) ? qt  + ((tb8 + 6 + li) << 9)
                             : kt  + ((tb8 + (li - 2)) << 9);
        } else if (nblk == 2) {
            gbase = (li < 4) ? kt  + ((tb8 + 4 + li) << 9)
                             : vtl + ((tb8 + (li - 4)) << 9);
        } else {
            gbase = vtl + ((tb8 + 2 + li) << 9);
        }
        *reinterpret_cast<short8*>(gbase + iu * 8) =
            *reinterpret_cast<const short8*>(&out_l[fb * 512 + iu * 8]);
    }
}

// ---------------------------------------------------------------------------
// Causal flash attention — round-17 structure (NS=4, grid 2048) + K-register
// prefetch (R10-proven-correct pattern, V-hoist omitted): kf for the NEXT
// tile is issued right after the QK MFMAs consume the current kf, hiding the
// ~200cy L2 latency under mask/softmax/pack. At NS=4 the grid wants only
// 8 waves/CU, so the VGPR cost cannot bind occupancy (R10's failure mode).
// ---------------------------------------------------------------------------
__global__ __launch_bounds__(64) void attn_kernel(
    const unsigned short* __restrict__ qt,
    const unsigned short* __restrict__ kt,
    const unsigned short* __restrict__ vtl,
    unsigned short* __restrict__ pacc,   // [NS][T32][128][32] bf16
    float* __restrict__ pm,
    float* __restrict__ pl)
{
    const int bid  = blockIdx.x;
    const int xcd  = bid & 7;
    const int b    = xcd >> 1;                // batch <-> XCD pair
    const int par  = xcd & 1;
    const int idx  = bid >> 3;                // 0..255 within XCD
    const int s    = idx & 3;                 // split (NS=4)
    const int trk  = idx >> 2;                // 0..63 tile-rank on this XCD
    const int t32b = (NT32 - 1) - (trk * 2 + par);   // longest first
    const int q0   = t32b * 32;
    const int t32  = b * NT32 + t32b;
    const int lane = threadIdx.x & 63;
    const int l31  = lane & 31;
    const int hih  = lane >> 5;

    const int nkv   = q0 + 32;
    const int chunk = ((nkv + NS * 32 - 1) / (NS * 32)) * 32;
    const int lo    = s * chunk;
    const int hikv  = (lo + chunk < nkv) ? lo + chunk : nkv;
    const size_t mlbase = (size_t)(s * T32 + t32) * 32;

    if (lo >= hikv) {
        if (lane < 32) { pm[mlbase + l31] = -3.0e38f; pl[mlbase + l31] = 0.f; }
        return;
    }

    // Q fragments (coalesced tiled loads)
    const unsigned short* qtb =
        qt + ((size_t)((b * NT32 + t32b) * 8) << 9) + lane * 8;
    short8 qa[8];
#pragma unroll
    for (int ks = 0; ks < 8; ++ks) qa[ks] = ld8(qtb + (ks << 9));

    const unsigned short* ktbase = kt  + ((size_t)(b * NT32 * 8) << 9) + lane * 8;
    const unsigned short* vtbase = vtl + ((size_t)(b * NT32 * 8) << 9) + lane * 8;

    floatx16 acco[4];
#pragma unroll
    for (int db = 0; db < 4; ++db)
#pragma unroll
        for (int i = 0; i < 16; ++i) acco[db][i] = 0.f;
    float m_r = -3.0e38f, l_r = 0.f;

    // K pipeline register: preload first tile
    short8 kf[8];
#pragma unroll
    for (int ks = 0; ks < 8; ++ks)
        kf[ks] = ld8(ktbase + ((size_t)((lo >> 5) * 8 + ks) << 9));

    for (int kv0 = lo; kv0 < hikv; kv0 += 32) {
        const int t = kv0 >> 5;
        const unsigned short* vtb = vtbase + ((size_t)(t * 8) << 9);

        // ---- scores S^T[kv][q] = mfma(K, Q) ----
        floatx16 sc;
#pragma unroll
        for (int i = 0; i < 16; ++i) sc[i] = 0.f;
#pragma unroll
        for (int ks = 0; ks < 8; ++ks)
            sc = __builtin_amdgcn_mfma_f32_32x32x16_bf16(kf[ks], qa[ks], sc, 0, 0, 0);

        // ---- prefetch next K tile (latency hides under softmax/pack) ----
        const int tn = (kv0 + 32 < hikv) ? t + 1 : t;
#pragma unroll
        for (int ks = 0; ks < 8; ++ks)
            kf[ks] = ld8(ktbase + ((size_t)(tn * 8 + ks) << 9));

        // ---- causal mask: only the diagonal tile ----
        if (kv0 == q0) {
#pragma unroll
            for (int r = 0; r < 16; ++r) {
                const int kvloc = (r & 3) + 8 * (r >> 2) + 4 * hih;
                if (kvloc > l31) sc[r] = -3.0e38f;
            }
        }
        // ---- lane-local max (tree) + cross-half ----
        float t8[8];
#pragma unroll
        for (int i = 0; i < 8; ++i) t8[i] = fmaxf(sc[i], sc[i + 8]);
        float t4a = fmaxf(t8[0], t8[4]), t4b = fmaxf(t8[1], t8[5]);
        float t4c = fmaxf(t8[2], t8[6]), t4d = fmaxf(t8[3], t8[7]);
        float pmax = fmaxf(fmaxf(t4a, t4b), fmaxf(t4c, t4d));
        pmax = fmaxf(pmax, __shfl_xor(pmax, 32));
        // ---- deferred rescale (T13, THR=8) ----
        if (__any(pmax > m_r + 8.f)) {
            const float mn  = fmaxf(m_r, pmax);
            const float fac = __expf(m_r - mn);
            m_r = mn; l_r *= fac;
#pragma unroll
            for (int db = 0; db < 4; ++db)
#pragma unroll
                for (int i = 0; i < 16; ++i) acco[db][i] *= fac;
        }
        // ---- p = exp(s - m), lane-local sum ----
        float p[16];
#pragma unroll
        for (int r = 0; r < 16; ++r) p[r] = __expf(sc[r] - m_r);
        float s8[8];
#pragma unroll
        for (int i = 0; i < 8; ++i) s8[i] = p[i] + p[i + 8];
        float s4a = s8[0] + s8[4], s4b = s8[1] + s8[5];
        float s4c = s8[2] + s8[6], s4d = s8[3] + s8[7];
        float ps = (s4a + s4b) + (s4c + s4d);
        ps += __shfl_xor(ps, 32);
        l_r += ps;
        // ---- pack P^T B-fragments (T12: cvt_pk + permlane32_swap) ----
        u32 pk0 = cvtpk_bf16(p[0], p[1]),   pk2 = cvtpk_bf16(p[4], p[5]);
        swap_halves(pk0, pk2);
        u32 pk1 = cvtpk_bf16(p[2], p[3]),   pk3 = cvtpk_bf16(p[6], p[7]);
        swap_halves(pk1, pk3);
        u32 pk4 = cvtpk_bf16(p[8], p[9]),   pk6 = cvtpk_bf16(p[12], p[13]);
        swap_halves(pk4, pk6);
        u32 pk5 = cvtpk_bf16(p[10], p[11]), pk7 = cvtpk_bf16(p[14], p[15]);
        swap_halves(pk5, pk7);
        union { u32 u[4]; short8 s8v; } ua, ub;
        ua.u[0] = pk0; ua.u[1] = pk1; ua.u[2] = pk2; ua.u[3] = pk3;
        ub.u[0] = pk4; ub.u[1] = pk5; ub.u[2] = pk6; ub.u[3] = pk7;
        const short8 pa0 = ua.s8v, pa1 = ub.s8v;
        // ---- PV: O^T[d][q] += V^T x P^T (coalesced tiled V loads) ----
#pragma unroll
        for (int db = 0; db < 4; ++db) {
            short8 vf0 = ld8(vtb + ((db * 2)     << 9));
            acco[db] = __builtin_amdgcn_mfma_f32_32x32x16_bf16(vf0, pa0, acco[db], 0, 0, 0);
            short8 vf1 = ld8(vtb + ((db * 2 + 1) << 9));
            acco[db] = __builtin_amdgcn_mfma_f32_32x32x16_bf16(vf1, pa1, acco[db], 0, 0, 0);
        }
    }

    // ---- write partials (bf16, transposed, coalesced over q) ----
    unsigned short* pt = pacc + (size_t)(s * T32 + t32) * 128 * 32;
#pragma unroll
    for (int db = 0; db < 4; ++db)
#pragma unroll
        for (int r = 0; r < 16; ++r) {
            const int dloc = db * 32 + (r & 3) + 8 * (r >> 2) + 4 * hih;
            pt[(size_t)dloc * 32 + l31] = (unsigned short)f2bf(acco[db][r]);
        }
    if (lane < 32) { pm[mlbase + l31] = m_r; pl[mlbase + l31] = l_r; }
}

// ---------------------------------------------------------------------------
// Combine NS bf16 partials per 32-row tile; LDS transpose for coalesced output.
// ---------------------------------------------------------------------------
__global__ __launch_bounds__(256) void combine_kernel(
    const unsigned short* __restrict__ pacc, const float* __restrict__ pm,
    const float* __restrict__ pl, float* __restrict__ out)
{
    __shared__ float wlds[NS][32];
    __shared__ float tlds[128][33];
    const int t32 = blockIdx.x;
    const int tid = threadIdx.x;

    if (tid < 32) {
        const int q = tid;
        float ms[NS], ls[NS];
        float M = -3.0e38f;
#pragma unroll
        for (int s = 0; s < NS; ++s) {
            ms[s] = pm[(size_t)(s * T32 + t32) * 32 + q];
            ls[s] = pl[(size_t)(s * T32 + t32) * 32 + q];
            M = fmaxf(M, ms[s]);
        }
        float w[NS], den = 0.f;
#pragma unroll
        for (int s = 0; s < NS; ++s) { w[s] = __expf(ms[s] - M); den += w[s] * ls[s]; }
        const float inv = 1.f / den;
#pragma unroll
        for (int s = 0; s < NS; ++s) wlds[s][q] = w[s] * inv;
    }
    __syncthreads();

#pragma unroll
    for (int rep = 0; rep < 16; ++rep) {
        const int flat = rep * 256 + tid;
        const int d = flat >> 5, q = flat & 31;
        float acc = 0.f;
#pragma unroll
        for (int s = 0; s < NS; ++s)
            acc += wlds[s][q] *
                   bf2f(pacc[((size_t)(s * T32 + t32) * 128 + d) * 32 + q]);
        tlds[d][q] = acc;
    }
    __syncthreads();

    const size_t row0 = (size_t)t32 * 32;
#pragma unroll
    for (int rep = 0; rep < 16; ++rep) {
        const int flat = rep * 256 + tid;
        const int q = flat >> 7, d = flat & 127;
        out[(row0 + q) * 128 + d] = tlds[d][q];
    }
}

// ---------------------------------------------------------------------------
extern "C" void kernel_launch(void* const* d_in, const int* in_sizes, int n_in,
                              void* d_out, int out_size, void* d_ws, size_t ws_size,
                              hipStream_t stream)
{
    const float* x  = (const float*)d_in[0];
    const float* Wq = (const float*)d_in[1];
    const float* Wk = (const float*)d_in[2];
    const float* Wv = (const float*)d_in[3];
    float* out = (float*)d_out;

    const size_t TBUF = (size_t)BATCH * NT32 * 8 * 512;           // 2M shorts = 4MB

    unsigned short* wbf  = (unsigned short*)d_ws;                 // 384*1024 bf16
    unsigned short* qt   = wbf + (size_t)384 * DMODEL;
    unsigned short* ktb  = qt + TBUF;
    unsigned short* vtl  = ktb + TBUF;
    unsigned short* pacc = vtl + TBUF;                            // NS*512*128*32 bf16 = 16MB
    float* pm = (float*)(pacc + (size_t)NS * T32 * 128 * 32);
    float* pl = pm + (size_t)NS * T32 * 32;
    // total ~29.3 MB

    const int n8w3 = 3 * HDIM * DMODEL / 8;
    cvt_w_kernel<<<(n8w3 + 255) / 256, 256, 0, stream>>>(Wq, Wk, Wv, wbf);

    qkv_kernel<<<(MROWS / BM) * (384 / BN), 256, 0, stream>>>(x, wbf, qt, ktb, vtl);

    attn_kernel<<<T32 * NS, 64, 0, stream>>>(qt, ktb, vtl, pacc, pm, pl);

    combine_kernel<<<T32, 256, 0, stream>>>(pacc, pm, pl, out);
}

// Round 20
// 84.431 us; speedup vs baseline: 1.2995x; 1.0297x over previous
//
#include <hip/hip_runtime.h>
#include <hip/hip_bf16.h>

#define BATCH  4
#define SEQ    4096
#define DMODEL 1024
#define HDIM   128
#define MROWS  (BATCH * SEQ)   // 16384
#define NT32   (SEQ / 32)      // 128 q-tiles (32 rows) per batch
#define T32    (BATCH * NT32)  // 512
#define NS     4               // KV splits per q-tile (bf16 partials)

// qkv GEMM tile (round-12/16 proven geometry)
#define BM 64
#define BN 96
#define BK 64
#define KT (DMODEL / BK)       // 16

typedef __attribute__((ext_vector_type(8)))  short short8;
typedef __attribute__((ext_vector_type(4)))  float floatx4;
typedef __attribute__((ext_vector_type(16))) float floatx16;
typedef unsigned int u32;

static __device__ __forceinline__ short f2bf(float f) {
    __hip_bfloat16 h = __float2bfloat16(f);
    union { __hip_bfloat16 h; short s; } u; u.h = h;
    return u.s;
}

static __device__ __forceinline__ float bf2f(unsigned short s) {
    union { u32 u; float f; } v; v.u = ((u32)s) << 16;
    return v.f;
}

static __device__ __forceinline__ short8 ld8(const unsigned short* p) {
    return *reinterpret_cast<const short8*>(p);
}

// async global->LDS, 16 B per lane; LDS dest = wave-uniform base + lane*16.
static __device__ __forceinline__ void gload_lds16(const void* g, void* l) {
    __builtin_amdgcn_global_load_lds(
        (const __attribute__((address_space(1))) unsigned int*)g,
        (__attribute__((address_space(3))) unsigned int*)l,
        16, 0, 0);
}

// pack two f32 -> one u32 of two bf16 (lo = a, hi = b)
static __device__ __forceinline__ u32 cvtpk_bf16(float a, float b) {
    u32 r;
    asm("v_cvt_pk_bf16_f32 %0, %1, %2" : "=v"(r) : "v"(a), "v"(b));
    return r;
}

// a' = {lanes<32: a ; lanes>=32: b from partner(lane-32)}
// b' = {lanes<32: a from partner(lane+32) ; lanes>=32: b}
static __device__ __forceinline__ void swap_halves(u32& a, u32& b) {
#if __has_builtin(__builtin_amdgcn_permlane32_swap)
    typedef __attribute__((ext_vector_type(2))) int int2v;
    int2v r = __builtin_amdgcn_permlane32_swap((int)a, (int)b, false, false);
    a = (u32)r[0]; b = (u32)r[1];
#else
    u32 ap = (u32)__shfl_xor((int)a, 32);
    u32 bp = (u32)__shfl_xor((int)b, 32);
    const bool hih = (threadIdx.x & 32) != 0;
    u32 na = hih ? bp : a;
    u32 nb = hih ? b : ap;
    a = na; b = nb;
#endif
}

// ===========================================================================
// FRAGMENT-TILED LAYOUTS (round-12 proven — attn loads are 1KB coalesced):
//  qt/kt: (b,s,d) at ((b*NT32+s/32)*8 + d/16)*512 + ((d/8)%2*32 + s%32)*8 + d%8
//  vtl:   (b,s,d) at ((b*NT32+s/32)*8 + (d/32)*2 + (s%32)/16)*512
//                     + ((s/8)%2*32 + d%32)*8 + s%8
// ===========================================================================

// ---------------------------------------------------------------------------
// W = [Wq;Wk;Wv] fp32 -> bf16, Wq pre-scaled by 1/sqrt(H). One launch.
// ---------------------------------------------------------------------------
__global__ __launch_bounds__(256) void cvt_w_kernel(
    const float* __restrict__ Wq, const float* __restrict__ Wk,
    const float* __restrict__ Wv, unsigned short* __restrict__ wbf)
{
    const int n8w = HDIM * DMODEL / 8;                // 16384
    int i = blockIdx.x * 256 + threadIdx.x;
    if (i >= 3 * n8w) return;
    const int which = i / n8w;
    const int j = i - which * n8w;
    const float* src = (which == 0) ? Wq : (which == 1) ? Wk : Wv;
    const float scale = (which == 0) ? 0.08838834764831845f : 1.0f;
    const float4* s4 = reinterpret_cast<const float4*>(src);
    float4 a = s4[2 * j];
    float4 b = s4[2 * j + 1];
    short8 o;
    o[0] = f2bf(a.x * scale); o[1] = f2bf(a.y * scale);
    o[2] = f2bf(a.z * scale); o[3] = f2bf(a.w * scale);
    o[4] = f2bf(b.x * scale); o[5] = f2bf(b.y * scale);
    o[6] = f2bf(b.z * scale); o[7] = f2bf(b.w * scale);
    reinterpret_cast<short8*>(wbf)[i] = o;
}

// ---------------------------------------------------------------------------
// QKV projection, double-buffered LDS GEMM (round-16 proven, unchanged).
// ---------------------------------------------------------------------------
__global__ __launch_bounds__(256, 4) void qkv_kernel(
    const float* __restrict__ x,             // [MROWS][DMODEL] fp32
    const unsigned short* __restrict__ wbf,  // [384][DMODEL] bf16
    unsigned short* __restrict__ qt,         // tiled Q
    unsigned short* __restrict__ kt,         // tiled K
    unsigned short* __restrict__ vtl)        // tiled V
{
    __shared__ __align__(16) unsigned short A_lds[2][BM][BK];  // 16 KB
    __shared__ __align__(16) unsigned short B_lds[2][BN][BK];  // 24 KB

    const int raw  = blockIdx.x;
    const int vid  = (raw & 7) * 128 + (raw >> 3);
    const int mblk = vid >> 2;
    const int nblk = vid & 3;
    const int m0   = mblk * BM;
    const int n0   = nblk * BN;

    const int tid  = threadIdx.x;
    const int wv   = tid >> 6;
    const int lane = tid & 63;
    const int lr   = lane & 15;
    const int lh   = lane >> 4;
    const int wm   = wv >> 1;   // 0/1 -> M offset 0/32
    const int wn   = wv & 1;    // 0/1 -> N offset 0/48

    const int ar = tid >> 2;
    const int aq = tid & 3;
    const float* asrc = x + (size_t)(m0 + ar) * DMODEL + aq * 16;

    const int brow  = lane >> 3;
    const int bunit = (lane & 7) ^ brow;

    floatx4 acc[2][3];
#pragma unroll
    for (int mf = 0; mf < 2; ++mf)
#pragma unroll
        for (int nf = 0; nf < 3; ++nf) acc[mf][nf] = (floatx4){0.f, 0.f, 0.f, 0.f};

    // ---- prologue: stage tile 0 into buffer 0 ----
    {
#pragma unroll
        for (int j = 0; j < 3; ++j) {
            const int rbase = (j * 4 + wv) * 8;
            gload_lds16(wbf + (size_t)(n0 + rbase + brow) * DMODEL + bunit * 8,
                        &B_lds[0][rbase][0]);
        }
        float4 f0 = *reinterpret_cast<const float4*>(asrc);
        float4 f1 = *reinterpret_cast<const float4*>(asrc + 4);
        float4 f2 = *reinterpret_cast<const float4*>(asrc + 8);
        float4 f3 = *reinterpret_cast<const float4*>(asrc + 12);
        short8 v0, v1;
        v0[0] = f2bf(f0.x); v0[1] = f2bf(f0.y); v0[2] = f2bf(f0.z); v0[3] = f2bf(f0.w);
        v0[4] = f2bf(f1.x); v0[5] = f2bf(f1.y); v0[6] = f2bf(f1.z); v0[7] = f2bf(f1.w);
        v1[0] = f2bf(f2.x); v1[1] = f2bf(f2.y); v1[2] = f2bf(f2.z); v1[3] = f2bf(f2.w);
        v1[4] = f2bf(f3.x); v1[5] = f2bf(f3.y); v1[6] = f2bf(f3.z); v1[7] = f2bf(f3.w);
        const int u0 = (2 * aq)     ^ (ar & 7);
        const int u1 = (2 * aq + 1) ^ (ar & 7);
        *reinterpret_cast<short8*>(&A_lds[0][ar][u0 * 8]) = v0;
        *reinterpret_cast<short8*>(&A_lds[0][ar][u1 * 8]) = v1;
    }
    __syncthreads();

    for (int ktile = 0; ktile < KT; ++ktile) {
        const int cur = ktile & 1;
        const int nxt = cur ^ 1;
        float4 f0, f1, f2, f3;
        if (ktile + 1 < KT) {
#pragma unroll
            for (int j = 0; j < 3; ++j) {
                const int rbase = (j * 4 + wv) * 8;
                gload_lds16(wbf + (size_t)(n0 + rbase + brow) * DMODEL
                                + (ktile + 1) * BK + bunit * 8,
                            &B_lds[nxt][rbase][0]);
            }
            const float* a = asrc + (ktile + 1) * BK;
            f0 = *reinterpret_cast<const float4*>(a);
            f1 = *reinterpret_cast<const float4*>(a + 4);
            f2 = *reinterpret_cast<const float4*>(a + 8);
            f3 = *reinterpret_cast<const float4*>(a + 12);
        }
#pragma unroll
        for (int kk = 0; kk < 2; ++kk) {
            const int uswz = (kk * 4 + lh) ^ (lr & 7);
            short8 af[2], bfr[3];
#pragma unroll
            for (int mf = 0; mf < 2; ++mf)
                af[mf] = ld8(&A_lds[cur][wm * 32 + mf * 16 + lr][uswz * 8]);
#pragma unroll
            for (int nf = 0; nf < 3; ++nf)
                bfr[nf] = ld8(&B_lds[cur][wn * 48 + nf * 16 + lr][uswz * 8]);
#pragma unroll
            for (int mf = 0; mf < 2; ++mf)
#pragma unroll
                for (int nf = 0; nf < 3; ++nf)
                    acc[mf][nf] = __builtin_amdgcn_mfma_f32_16x16x32_bf16(
                        af[mf], bfr[nf], acc[mf][nf], 0, 0, 0);
        }
        if (ktile + 1 < KT) {
            short8 v0, v1;
            v0[0] = f2bf(f0.x); v0[1] = f2bf(f0.y); v0[2] = f2bf(f0.z); v0[3] = f2bf(f0.w);
            v0[4] = f2bf(f1.x); v0[5] = f2bf(f1.y); v0[6] = f2bf(f1.z); v0[7] = f2bf(f1.w);
            v1[0] = f2bf(f2.x); v1[1] = f2bf(f2.y); v1[2] = f2bf(f2.z); v1[3] = f2bf(f2.w);
            v1[4] = f2bf(f3.x); v1[5] = f2bf(f3.y); v1[6] = f2bf(f3.z); v1[7] = f2bf(f3.w);
            const int u0 = (2 * aq)     ^ (ar & 7);
            const int u1 = (2 * aq + 1) ^ (ar & 7);
            *reinterpret_cast<short8*>(&A_lds[nxt][ar][u0 * 8]) = v0;
            *reinterpret_cast<short8*>(&A_lds[nxt][ar][u1 * 8]) = v1;
        }
        __syncthreads();
    }

    // ======== epilogue: LDS-staged, coalesced copy-out (round-16 proven) ====
    __syncthreads();
    unsigned short* out_l = &A_lds[0][0][0];   // 12KB image

    const int t0 = (m0 & (SEQ - 1)) >> 5;
    const int bb = m0 >> 12;
    const int st = wm;

#pragma unroll
    for (int nf = 0; nf < 3; ++nf) {
        const int cl = wn * 48 + nf * 16 + lr;
#pragma unroll
        for (int mf = 0; mf < 2; ++mf) {
#pragma unroll
            for (int r = 0; r < 4; ++r) {
                const int srow = mf * 16 + lh * 4 + r;
                const unsigned short vv = (unsigned short)f2bf(acc[mf][nf][r]);
                int lf, off;
                if (nblk == 0) {
                    lf  = st * 6 + (cl >> 4);
                    off = ((cl >> 3) & 1) * 256 + srow * 8 + (cl & 7);
                } else if (nblk == 1) {
                    lf  = (cl < 32) ? st * 6 + (cl >> 4)
                                    : st * 6 + 2 + ((cl - 32) >> 4);
                    off = ((cl >> 3) & 1) * 256 + srow * 8 + (cl & 7);
                } else if (nblk == 2) {
                    if (cl < 64) {
                        lf  = st * 6 + (cl >> 4);
                        off = ((cl >> 3) & 1) * 256 + srow * 8 + (cl & 7);
                    } else {
                        const int dg = cl - 64;
                        lf  = st * 6 + 4 + ((srow >> 4) & 1);
                        off = ((srow >> 3) & 1) * 256 + dg * 8 + (srow & 7);
                    }
                } else {
                    const int d = cl + 32;
                    lf  = st * 6 + ((d >> 5) - 1) * 2 + ((srow >> 4) & 1);
                    off = ((srow >> 3) & 1) * 256 + (d & 31) * 8 + (srow & 7);
                }
                out_l[lf * 512 + off] = vv;
            }
        }
    }
    __syncthreads();

#pragma unroll
    for (int k = 0; k < 3; ++k) {
        const int u   = tid + 256 * k;
        const int fb  = u >> 6;
        const int iu  = u & 63;
        const int fst = (fb >= 6) ? 1 : 0;
        const int li  = fb - 6 * fst;
        const size_t tb8 = (size_t)((bb * NT32 + t0 + fst) * 8);
        unsigned short* gbase;
        if (nblk == 0) {
            gbase = qt + ((tb8 + li) << 9);
        } else if (nblk == 1) {
            gbase = (li < 2) ? qt  + ((tb8 + 6 + li) << 9)
                             : kt  + ((tb8 + (li - 2)) << 9);
        } else if (nblk == 2) {
            gbase = (li < 4) ? kt  + ((tb8 + 4 + li) << 9)
                             : vtl + ((tb8 + (li - 4)) << 9);
        } else {
            gbase = vtl + ((tb8 + 2 + li) << 9);
        }
        *reinterpret_cast<short8*>(gbase + iu * 8) =
            *reinterpret_cast<const short8*>(&out_l[fb * 512 + iu * 8]);
    }
}

// ---------------------------------------------------------------------------
// Causal flash attention — round-19 structure (NS=4, K-register prefetch)
// + V-issue-early (R10's proven-correct pattern): vf for the CURRENT tile is
// issued at loop top, consumed after softmax/pack (~400cy later) — hides the
// V L2 latency. At NS=4 the grid wants 8 waves/CU, so the added VGPR
// (~135-145) cannot bind occupancy (R10's NS=8 failure mode).
// ---------------------------------------------------------------------------
__global__ __launch_bounds__(64) void attn_kernel(
    const unsigned short* __restrict__ qt,
    const unsigned short* __restrict__ kt,
    const unsigned short* __restrict__ vtl,
    unsigned short* __restrict__ pacc,   // [NS][T32][128][32] bf16
    float* __restrict__ pm,
    float* __restrict__ pl)
{
    const int bid  = blockIdx.x;
    const int xcd  = bid & 7;
    const int b    = xcd >> 1;                // batch <-> XCD pair
    const int par  = xcd & 1;
    const int idx  = bid >> 3;                // 0..255 within XCD
    const int s    = idx & 3;                 // split (NS=4)
    const int trk  = idx >> 2;                // 0..63 tile-rank on this XCD
    const int t32b = (NT32 - 1) - (trk * 2 + par);   // longest first
    const int q0   = t32b * 32;
    const int t32  = b * NT32 + t32b;
    const int lane = threadIdx.x & 63;
    const int l31  = lane & 31;
    const int hih  = lane >> 5;

    const int nkv   = q0 + 32;
    const int chunk = ((nkv + NS * 32 - 1) / (NS * 32)) * 32;
    const int lo    = s * chunk;
    const int hikv  = (lo + chunk < nkv) ? lo + chunk : nkv;
    const size_t mlbase = (size_t)(s * T32 + t32) * 32;

    if (lo >= hikv) {
        if (lane < 32) { pm[mlbase + l31] = -3.0e38f; pl[mlbase + l31] = 0.f; }
        return;
    }

    // Q fragments (coalesced tiled loads)
    const unsigned short* qtb =
        qt + ((size_t)((b * NT32 + t32b) * 8) << 9) + lane * 8;
    short8 qa[8];
#pragma unroll
    for (int ks = 0; ks < 8; ++ks) qa[ks] = ld8(qtb + (ks << 9));

    const unsigned short* ktbase = kt  + ((size_t)(b * NT32 * 8) << 9) + lane * 8;
    const unsigned short* vtbase = vtl + ((size_t)(b * NT32 * 8) << 9) + lane * 8;

    floatx16 acco[4];
#pragma unroll
    for (int db = 0; db < 4; ++db)
#pragma unroll
        for (int i = 0; i < 16; ++i) acco[db][i] = 0.f;
    float m_r = -3.0e38f, l_r = 0.f;

    // K pipeline register: preload first tile
    short8 kf[8];
#pragma unroll
    for (int ks = 0; ks < 8; ++ks)
        kf[ks] = ld8(ktbase + ((size_t)((lo >> 5) * 8 + ks) << 9));

    for (int kv0 = lo; kv0 < hikv; kv0 += 32) {
        const int t = kv0 >> 5;
        const unsigned short* vtb = vtbase + ((size_t)(t * 8) << 9);

        // ---- V for current tile: issue early, consumed after softmax ----
        short8 vf[8];
#pragma unroll
        for (int j = 0; j < 8; ++j) vf[j] = ld8(vtb + (j << 9));

        // ---- scores S^T[kv][q] = mfma(K, Q) ----
        floatx16 sc;
#pragma unroll
        for (int i = 0; i < 16; ++i) sc[i] = 0.f;
#pragma unroll
        for (int ks = 0; ks < 8; ++ks)
            sc = __builtin_amdgcn_mfma_f32_32x32x16_bf16(kf[ks], qa[ks], sc, 0, 0, 0);

        // ---- prefetch next K tile (latency hides under softmax/pack) ----
        const int tn = (kv0 + 32 < hikv) ? t + 1 : t;
#pragma unroll
        for (int ks = 0; ks < 8; ++ks)
            kf[ks] = ld8(ktbase + ((size_t)(tn * 8 + ks) << 9));

        // ---- causal mask: only the diagonal tile ----
        if (kv0 == q0) {
#pragma unroll
            for (int r = 0; r < 16; ++r) {
                const int kvloc = (r & 3) + 8 * (r >> 2) + 4 * hih;
                if (kvloc > l31) sc[r] = -3.0e38f;
            }
        }
        // ---- lane-local max (tree) + cross-half ----
        float t8[8];
#pragma unroll
        for (int i = 0; i < 8; ++i) t8[i] = fmaxf(sc[i], sc[i + 8]);
        float t4a = fmaxf(t8[0], t8[4]), t4b = fmaxf(t8[1], t8[5]);
        float t4c = fmaxf(t8[2], t8[6]), t4d = fmaxf(t8[3], t8[7]);
        float pmax = fmaxf(fmaxf(t4a, t4b), fmaxf(t4c, t4d));
        pmax = fmaxf(pmax, __shfl_xor(pmax, 32));
        // ---- deferred rescale (T13, THR=8) ----
        if (__any(pmax > m_r + 8.f)) {
            const float mn  = fmaxf(m_r, pmax);
            const float fac = __expf(m_r - mn);
            m_r = mn; l_r *= fac;
#pragma unroll
            for (int db = 0; db < 4; ++db)
#pragma unroll
                for (int i = 0; i < 16; ++i) acco[db][i] *= fac;
        }
        // ---- p = exp(s - m), lane-local sum ----
        float p[16];
#pragma unroll
        for (int r = 0; r < 16; ++r) p[r] = __expf(sc[r] - m_r);
        float s8[8];
#pragma unroll
        for (int i = 0; i < 8; ++i) s8[i] = p[i] + p[i + 8];
        float s4a = s8[0] + s8[4], s4b = s8[1] + s8[5];
        float s4c = s8[2] + s8[6], s4d = s8[3] + s8[7];
        float ps = (s4a + s4b) + (s4c + s4d);
        ps += __shfl_xor(ps, 32);
        l_r += ps;
        // ---- pack P^T B-fragments (T12: cvt_pk + permlane32_swap) ----
        u32 pk0 = cvtpk_bf16(p[0], p[1]),   pk2 = cvtpk_bf16(p[4], p[5]);
        swap_halves(pk0, pk2);
        u32 pk1 = cvtpk_bf16(p[2], p[3]),   pk3 = cvtpk_bf16(p[6], p[7]);
        swap_halves(pk1, pk3);
        u32 pk4 = cvtpk_bf16(p[8], p[9]),   pk6 = cvtpk_bf16(p[12], p[13]);
        swap_halves(pk4, pk6);
        u32 pk5 = cvtpk_bf16(p[10], p[11]), pk7 = cvtpk_bf16(p[14], p[15]);
        swap_halves(pk5, pk7);
        union { u32 u[4]; short8 s8v; } ua, ub;
        ua.u[0] = pk0; ua.u[1] = pk1; ua.u[2] = pk2; ua.u[3] = pk3;
        ub.u[0] = pk4; ub.u[1] = pk5; ub.u[2] = pk6; ub.u[3] = pk7;
        const short8 pa0 = ua.s8v, pa1 = ub.s8v;
        // ---- PV: O^T[d][q] += V^T x P^T (vf already in registers) ----
#pragma unroll
        for (int db = 0; db < 4; ++db) {
            acco[db] = __builtin_amdgcn_mfma_f32_32x32x16_bf16(vf[2 * db],     pa0, acco[db], 0, 0, 0);
            acco[db] = __builtin_amdgcn_mfma_f32_32x32x16_bf16(vf[2 * db + 1], pa1, acco[db], 0, 0, 0);
        }
    }

    // ---- write partials (bf16, transposed, coalesced over q) ----
    unsigned short* pt = pacc + (size_t)(s * T32 + t32) * 128 * 32;
#pragma unroll
    for (int db = 0; db < 4; ++db)
#pragma unroll
        for (int r = 0; r < 16; ++r) {
            const int dloc = db * 32 + (r & 3) + 8 * (r >> 2) + 4 * hih;
            pt[(size_t)dloc * 32 + l31] = (unsigned short)f2bf(acco[db][r]);
        }
    if (lane < 32) { pm[mlbase + l31] = m_r; pl[mlbase + l31] = l_r; }
}

// ---------------------------------------------------------------------------
// Combine NS bf16 partials per 32-row tile; LDS transpose for coalesced output.
// ---------------------------------------------------------------------------
__global__ __launch_bounds__(256) void combine_kernel(
    const unsigned short* __restrict__ pacc, const float* __restrict__ pm,
    const float* __restrict__ pl, float* __restrict__ out)
{
    __shared__ float wlds[NS][32];
    __shared__ float tlds[128][33];
    const int t32 = blockIdx.x;
    const int tid = threadIdx.x;

    if (tid < 32) {
        const int q = tid;
        float ms[NS], ls[NS];
        float M = -3.0e38f;
#pragma unroll
        for (int s = 0; s < NS; ++s) {
            ms[s] = pm[(size_t)(s * T32 + t32) * 32 + q];
            ls[s] = pl[(size_t)(s * T32 + t32) * 32 + q];
            M = fmaxf(M, ms[s]);
        }
        float w[NS], den = 0.f;
#pragma unroll
        for (int s = 0; s < NS; ++s) { w[s] = __expf(ms[s] - M); den += w[s] * ls[s]; }
        const float inv = 1.f / den;
#pragma unroll
        for (int s = 0; s < NS; ++s) wlds[s][q] = w[s] * inv;
    }
    __syncthreads();

#pragma unroll
    for (int rep = 0; rep < 16; ++rep) {
        const int flat = rep * 256 + tid;
        const int d = flat >> 5, q = flat & 31;
        float acc = 0.f;
#pragma unroll
        for (int s = 0; s < NS; ++s)
            acc += wlds[s][q] *
                   bf2f(pacc[((size_t)(s * T32 + t32) * 128 + d) * 32 + q]);
        tlds[d][q] = acc;
    }
    __syncthreads();

    const size_t row0 = (size_t)t32 * 32;
#pragma unroll
    for (int rep = 0; rep < 16; ++rep) {
        const int flat = rep * 256 + tid;
        const int q = flat >> 7, d = flat & 127;
        out[(row0 + q) * 128 + d] = tlds[d][q];
    }
}

// ---------------------------------------------------------------------------
extern "C" void kernel_launch(void* const* d_in, const int* in_sizes, int n_in,
                              void* d_out, int out_size, void* d_ws, size_t ws_size,
                              hipStream_t stream)
{
    const float* x  = (const float*)d_in[0];
    const float* Wq = (const float*)d_in[1];
    const float* Wk = (const float*)d_in[2];
    const float* Wv = (const float*)d_in[3];
    float* out = (float*)d_out;

    const size_t TBUF = (size_t)BATCH * NT32 * 8 * 512;           // 2M shorts = 4MB

    unsigned short* wbf  = (unsigned short*)d_ws;                 // 384*1024 bf16
    unsigned short* qt   = wbf + (size_t)384 * DMODEL;
    unsigned short* ktb  = qt + TBUF;
    unsigned short* vtl  = ktb + TBUF;
    unsigned short* pacc = vtl + TBUF;                            // NS*512*128*32 bf16 = 16MB
    float* pm = (float*)(pacc + (size_t)NS * T32 * 128 * 32);
    float* pl = pm + (size_t)NS * T32 * 32;
    // total ~29.3 MB

    const int n8w3 = 3 * HDIM * DMODEL / 8;
    cvt_w_kernel<<<(n8w3 + 255) / 256, 256, 0, stream>>>(Wq, Wk, Wv, wbf);

    qkv_kernel<<<(MROWS / BM) * (384 / BN), 256, 0, stream>>>(x, wbf, qt, ktb, vtl);

    attn_kernel<<<T32 * NS, 64, 0, stream>>>(qt, ktb, vtl, pacc, pm, pl);

    combine_kernel<<<T32, 256, 0, stream>>>(pacc, pm, pl, out);
}

// Round 21
// 79.662 us; speedup vs baseline: 1.3773x; 1.0599x over previous
//
#include <hip/hip_runtime.h>
#include <hip/hip_bf16.h>

#define BATCH  4
#define SEQ    4096
#define DMODEL 1024
#define HDIM   128
#define MROWS  (BATCH * SEQ)   // 16384
#define NT32   (SEQ / 32)      // 128 q-tiles (32 rows) per batch
#define T32    (BATCH * NT32)  // 512
#define NS     4               // KV splits per q-tile (bf16 partials)

// qkv GEMM tile (round-12/16 proven geometry)
#define BM 64
#define BN 96
#define BK 64
#define KT (DMODEL / BK)       // 16

typedef __attribute__((ext_vector_type(8)))  short short8;
typedef __attribute__((ext_vector_type(4)))  float floatx4;
typedef __attribute__((ext_vector_type(16))) float floatx16;
typedef unsigned int u32;

static __device__ __forceinline__ short f2bf(float f) {
    __hip_bfloat16 h = __float2bfloat16(f);
    union { __hip_bfloat16 h; short s; } u; u.h = h;
    return u.s;
}

static __device__ __forceinline__ float bf2f(unsigned short s) {
    union { u32 u; float f; } v; v.u = ((u32)s) << 16;
    return v.f;
}

static __device__ __forceinline__ short8 ld8(const unsigned short* p) {
    return *reinterpret_cast<const short8*>(p);
}

// async global->LDS, 16 B per lane; LDS dest = wave-uniform base + lane*16.
static __device__ __forceinline__ void gload_lds16(const void* g, void* l) {
    __builtin_amdgcn_global_load_lds(
        (const __attribute__((address_space(1))) unsigned int*)g,
        (__attribute__((address_space(3))) unsigned int*)l,
        16, 0, 0);
}

// pack two f32 -> one u32 of two bf16 (lo = a, hi = b)
static __device__ __forceinline__ u32 cvtpk_bf16(float a, float b) {
    u32 r;
    asm("v_cvt_pk_bf16_f32 %0, %1, %2" : "=v"(r) : "v"(a), "v"(b));
    return r;
}

// a' = {lanes<32: a ; lanes>=32: b from partner(lane-32)}
// b' = {lanes<32: a from partner(lane+32) ; lanes>=32: b}
static __device__ __forceinline__ void swap_halves(u32& a, u32& b) {
#if __has_builtin(__builtin_amdgcn_permlane32_swap)
    typedef __attribute__((ext_vector_type(2))) int int2v;
    int2v r = __builtin_amdgcn_permlane32_swap((int)a, (int)b, false, false);
    a = (u32)r[0]; b = (u32)r[1];
#else
    u32 ap = (u32)__shfl_xor((int)a, 32);
    u32 bp = (u32)__shfl_xor((int)b, 32);
    const bool hih = (threadIdx.x & 32) != 0;
    u32 na = hih ? bp : a;
    u32 nb = hih ? b : ap;
    a = na; b = nb;
#endif
}

// ===========================================================================
// FRAGMENT-TILED LAYOUTS (round-12 proven — attn loads are 1KB coalesced):
//  qt/kt: (b,s,d) at ((b*NT32+s/32)*8 + d/16)*512 + ((d/8)%2*32 + s%32)*8 + d%8
//  vtl:   (b,s,d) at ((b*NT32+s/32)*8 + (d/32)*2 + (s%32)/16)*512
//                     + ((s/8)%2*32 + d%32)*8 + s%8
// ===========================================================================

// ---------------------------------------------------------------------------
// W = [Wq;Wk;Wv] fp32 -> bf16, Wq pre-scaled by 1/sqrt(H). One launch.
// ---------------------------------------------------------------------------
__global__ __launch_bounds__(256) void cvt_w_kernel(
    const float* __restrict__ Wq, const float* __restrict__ Wk,
    const float* __restrict__ Wv, unsigned short* __restrict__ wbf)
{
    const int n8w = HDIM * DMODEL / 8;                // 16384
    int i = blockIdx.x * 256 + threadIdx.x;
    if (i >= 3 * n8w) return;
    const int which = i / n8w;
    const int j = i - which * n8w;
    const float* src = (which == 0) ? Wq : (which == 1) ? Wk : Wv;
    const float scale = (which == 0) ? 0.08838834764831845f : 1.0f;
    const float4* s4 = reinterpret_cast<const float4*>(src);
    float4 a = s4[2 * j];
    float4 b = s4[2 * j + 1];
    short8 o;
    o[0] = f2bf(a.x * scale); o[1] = f2bf(a.y * scale);
    o[2] = f2bf(a.z * scale); o[3] = f2bf(a.w * scale);
    o[4] = f2bf(b.x * scale); o[5] = f2bf(b.y * scale);
    o[6] = f2bf(b.z * scale); o[7] = f2bf(b.w * scale);
    reinterpret_cast<short8*>(wbf)[i] = o;
}

// ---------------------------------------------------------------------------
// QKV projection, double-buffered LDS GEMM (round-16 proven, unchanged).
// ---------------------------------------------------------------------------
__global__ __launch_bounds__(256, 4) void qkv_kernel(
    const float* __restrict__ x,             // [MROWS][DMODEL] fp32
    const unsigned short* __restrict__ wbf,  // [384][DMODEL] bf16
    unsigned short* __restrict__ qt,         // tiled Q
    unsigned short* __restrict__ kt,         // tiled K
    unsigned short* __restrict__ vtl)        // tiled V
{
    __shared__ __align__(16) unsigned short A_lds[2][BM][BK];  // 16 KB
    __shared__ __align__(16) unsigned short B_lds[2][BN][BK];  // 24 KB

    const int raw  = blockIdx.x;
    const int vid  = (raw & 7) * 128 + (raw >> 3);
    const int mblk = vid >> 2;
    const int nblk = vid & 3;
    const int m0   = mblk * BM;
    const int n0   = nblk * BN;

    const int tid  = threadIdx.x;
    const int wv   = tid >> 6;
    const int lane = tid & 63;
    const int lr   = lane & 15;
    const int lh   = lane >> 4;
    const int wm   = wv >> 1;   // 0/1 -> M offset 0/32
    const int wn   = wv & 1;    // 0/1 -> N offset 0/48

    const int ar = tid >> 2;
    const int aq = tid & 3;
    const float* asrc = x + (size_t)(m0 + ar) * DMODEL + aq * 16;

    const int brow  = lane >> 3;
    const int bunit = (lane & 7) ^ brow;

    floatx4 acc[2][3];
#pragma unroll
    for (int mf = 0; mf < 2; ++mf)
#pragma unroll
        for (int nf = 0; nf < 3; ++nf) acc[mf][nf] = (floatx4){0.f, 0.f, 0.f, 0.f};

    // ---- prologue: stage tile 0 into buffer 0 ----
    {
#pragma unroll
        for (int j = 0; j < 3; ++j) {
            const int rbase = (j * 4 + wv) * 8;
            gload_lds16(wbf + (size_t)(n0 + rbase + brow) * DMODEL + bunit * 8,
                        &B_lds[0][rbase][0]);
        }
        float4 f0 = *reinterpret_cast<const float4*>(asrc);
        float4 f1 = *reinterpret_cast<const float4*>(asrc + 4);
        float4 f2 = *reinterpret_cast<const float4*>(asrc + 8);
        float4 f3 = *reinterpret_cast<const float4*>(asrc + 12);
        short8 v0, v1;
        v0[0] = f2bf(f0.x); v0[1] = f2bf(f0.y); v0[2] = f2bf(f0.z); v0[3] = f2bf(f0.w);
        v0[4] = f2bf(f1.x); v0[5] = f2bf(f1.y); v0[6] = f2bf(f1.z); v0[7] = f2bf(f1.w);
        v1[0] = f2bf(f2.x); v1[1] = f2bf(f2.y); v1[2] = f2bf(f2.z); v1[3] = f2bf(f2.w);
        v1[4] = f2bf(f3.x); v1[5] = f2bf(f3.y); v1[6] = f2bf(f3.z); v1[7] = f2bf(f3.w);
        const int u0 = (2 * aq)     ^ (ar & 7);
        const int u1 = (2 * aq + 1) ^ (ar & 7);
        *reinterpret_cast<short8*>(&A_lds[0][ar][u0 * 8]) = v0;
        *reinterpret_cast<short8*>(&A_lds[0][ar][u1 * 8]) = v1;
    }
    __syncthreads();

    for (int ktile = 0; ktile < KT; ++ktile) {
        const int cur = ktile & 1;
        const int nxt = cur ^ 1;
        float4 f0, f1, f2, f3;
        if (ktile + 1 < KT) {
#pragma unroll
            for (int j = 0; j < 3; ++j) {
                const int rbase = (j * 4 + wv) * 8;
                gload_lds16(wbf + (size_t)(n0 + rbase + brow) * DMODEL
                                + (ktile + 1) * BK + bunit * 8,
                            &B_lds[nxt][rbase][0]);
            }
            const float* a = asrc + (ktile + 1) * BK;
            f0 = *reinterpret_cast<const float4*>(a);
            f1 = *reinterpret_cast<const float4*>(a + 4);
            f2 = *reinterpret_cast<const float4*>(a + 8);
            f3 = *reinterpret_cast<const float4*>(a + 12);
        }
#pragma unroll
        for (int kk = 0; kk < 2; ++kk) {
            const int uswz = (kk * 4 + lh) ^ (lr & 7);
            short8 af[2], bfr[3];
#pragma unroll
            for (int mf = 0; mf < 2; ++mf)
                af[mf] = ld8(&A_lds[cur][wm * 32 + mf * 16 + lr][uswz * 8]);
#pragma unroll
            for (int nf = 0; nf < 3; ++nf)
                bfr[nf] = ld8(&B_lds[cur][wn * 48 + nf * 16 + lr][uswz * 8]);
#pragma unroll
            for (int mf = 0; mf < 2; ++mf)
#pragma unroll
                for (int nf = 0; nf < 3; ++nf)
                    acc[mf][nf] = __builtin_amdgcn_mfma_f32_16x16x32_bf16(
                        af[mf], bfr[nf], acc[mf][nf], 0, 0, 0);
        }
        if (ktile + 1 < KT) {
            short8 v0, v1;
            v0[0] = f2bf(f0.x); v0[1] = f2bf(f0.y); v0[2] = f2bf(f0.z); v0[3] = f2bf(f0.w);
            v0[4] = f2bf(f1.x); v0[5] = f2bf(f1.y); v0[6] = f2bf(f1.z); v0[7] = f2bf(f1.w);
            v1[0] = f2bf(f2.x); v1[1] = f2bf(f2.y); v1[2] = f2bf(f2.z); v1[3] = f2bf(f2.w);
            v1[4] = f2bf(f3.x); v1[5] = f2bf(f3.y); v1[6] = f2bf(f3.z); v1[7] = f2bf(f3.w);
            const int u0 = (2 * aq)     ^ (ar & 7);
            const int u1 = (2 * aq + 1) ^ (ar & 7);
            *reinterpret_cast<short8*>(&A_lds[nxt][ar][u0 * 8]) = v0;
            *reinterpret_cast<short8*>(&A_lds[nxt][ar][u1 * 8]) = v1;
        }
        __syncthreads();
    }

    // ======== epilogue: LDS-staged, coalesced copy-out (round-16 proven) ====
    __syncthreads();
    unsigned short* out_l = &A_lds[0][0][0];   // 12KB image

    const int t0 = (m0 & (SEQ - 1)) >> 5;
    const int bb = m0 >> 12;
    const int st = wm;

#pragma unroll
    for (int nf = 0; nf < 3; ++nf) {
        const int cl = wn * 48 + nf * 16 + lr;
#pragma unroll
        for (int mf = 0; mf < 2; ++mf) {
#pragma unroll
            for (int r = 0; r < 4; ++r) {
                const int srow = mf * 16 + lh * 4 + r;
                const unsigned short vv = (unsigned short)f2bf(acc[mf][nf][r]);
                int lf, off;
                if (nblk == 0) {
                    lf  = st * 6 + (cl >> 4);
                    off = ((cl >> 3) & 1) * 256 + srow * 8 + (cl & 7);
                } else if (nblk == 1) {
                    lf  = (cl < 32) ? st * 6 + (cl >> 4)
                                    : st * 6 + 2 + ((cl - 32) >> 4);
                    off = ((cl >> 3) & 1) * 256 + srow * 8 + (cl & 7);
                } else if (nblk == 2) {
                    if (cl < 64) {
                        lf  = st * 6 + (cl >> 4);
                        off = ((cl >> 3) & 1) * 256 + srow * 8 + (cl & 7);
                    } else {
                        const int dg = cl - 64;
                        lf  = st * 6 + 4 + ((srow >> 4) & 1);
                        off = ((srow >> 3) & 1) * 256 + dg * 8 + (srow & 7);
                    }
                } else {
                    const int d = cl + 32;
                    lf  = st * 6 + ((d >> 5) - 1) * 2 + ((srow >> 4) & 1);
                    off = ((srow >> 3) & 1) * 256 + (d & 31) * 8 + (srow & 7);
                }
                out_l[lf * 512 + off] = vv;
            }
        }
    }
    __syncthreads();

#pragma unroll
    for (int k = 0; k < 3; ++k) {
        const int u   = tid + 256 * k;
        const int fb  = u >> 6;
        const int iu  = u & 63;
        const int fst = (fb >= 6) ? 1 : 0;
        const int li  = fb - 6 * fst;
        const size_t tb8 = (size_t)((bb * NT32 + t0 + fst) * 8);
        unsigned short* gbase;
        if (nblk == 0) {
            gbase = qt + ((tb8 + li) << 9);
        } else if (nblk == 1) {
            gbase = (li < 2) ? qt  + ((tb8 + 6 + li) << 9)
                             : kt  + ((tb8 + (li - 2)) << 9);
        } else if (nblk == 2) {
            gbase = (li < 4) ? kt  + ((tb8 + 4 + li) << 9)
                             : vtl + ((tb8 + (li - 4)) << 9);
        } else {
            gbase = vtl + ((tb8 + 2 + li) << 9);
        }
        *reinterpret_cast<short8*>(gbase + iu * 8) =
            *reinterpret_cast<const short8*>(&out_l[fb * 512 + iu * 8]);
    }
}

// ---------------------------------------------------------------------------
// Causal flash attention — round-20 structure (NS=4, K-prefetch, V-early)
// + T5 s_setprio(1) around both MFMA clusters: independent 1-wave blocks at
// different phases on a CU is exactly the m191 regime where priority lets
// MFMA-entering waves preempt load/VALU-issuing neighbors (+4-7%).
// ---------------------------------------------------------------------------
__global__ __launch_bounds__(64) void attn_kernel(
    const unsigned short* __restrict__ qt,
    const unsigned short* __restrict__ kt,
    const unsigned short* __restrict__ vtl,
    unsigned short* __restrict__ pacc,   // [NS][T32][128][32] bf16
    float* __restrict__ pm,
    float* __restrict__ pl)
{
    const int bid  = blockIdx.x;
    const int xcd  = bid & 7;
    const int b    = xcd >> 1;                // batch <-> XCD pair
    const int par  = xcd & 1;
    const int idx  = bid >> 3;                // 0..255 within XCD
    const int s    = idx & 3;                 // split (NS=4)
    const int trk  = idx >> 2;                // 0..63 tile-rank on this XCD
    const int t32b = (NT32 - 1) - (trk * 2 + par);   // longest first
    const int q0   = t32b * 32;
    const int t32  = b * NT32 + t32b;
    const int lane = threadIdx.x & 63;
    const int l31  = lane & 31;
    const int hih  = lane >> 5;

    const int nkv   = q0 + 32;
    const int chunk = ((nkv + NS * 32 - 1) / (NS * 32)) * 32;
    const int lo    = s * chunk;
    const int hikv  = (lo + chunk < nkv) ? lo + chunk : nkv;
    const size_t mlbase = (size_t)(s * T32 + t32) * 32;

    if (lo >= hikv) {
        if (lane < 32) { pm[mlbase + l31] = -3.0e38f; pl[mlbase + l31] = 0.f; }
        return;
    }

    // Q fragments (coalesced tiled loads)
    const unsigned short* qtb =
        qt + ((size_t)((b * NT32 + t32b) * 8) << 9) + lane * 8;
    short8 qa[8];
#pragma unroll
    for (int ks = 0; ks < 8; ++ks) qa[ks] = ld8(qtb + (ks << 9));

    const unsigned short* ktbase = kt  + ((size_t)(b * NT32 * 8) << 9) + lane * 8;
    const unsigned short* vtbase = vtl + ((size_t)(b * NT32 * 8) << 9) + lane * 8;

    floatx16 acco[4];
#pragma unroll
    for (int db = 0; db < 4; ++db)
#pragma unroll
        for (int i = 0; i < 16; ++i) acco[db][i] = 0.f;
    float m_r = -3.0e38f, l_r = 0.f;

    // K pipeline register: preload first tile
    short8 kf[8];
#pragma unroll
    for (int ks = 0; ks < 8; ++ks)
        kf[ks] = ld8(ktbase + ((size_t)((lo >> 5) * 8 + ks) << 9));

    for (int kv0 = lo; kv0 < hikv; kv0 += 32) {
        const int t = kv0 >> 5;
        const unsigned short* vtb = vtbase + ((size_t)(t * 8) << 9);

        // ---- V for current tile: issue early, consumed after softmax ----
        short8 vf[8];
#pragma unroll
        for (int j = 0; j < 8; ++j) vf[j] = ld8(vtb + (j << 9));

        // ---- scores S^T[kv][q] = mfma(K, Q) ----
        floatx16 sc;
#pragma unroll
        for (int i = 0; i < 16; ++i) sc[i] = 0.f;
        __builtin_amdgcn_s_setprio(1);
#pragma unroll
        for (int ks = 0; ks < 8; ++ks)
            sc = __builtin_amdgcn_mfma_f32_32x32x16_bf16(kf[ks], qa[ks], sc, 0, 0, 0);
        __builtin_amdgcn_s_setprio(0);

        // ---- prefetch next K tile (latency hides under softmax/pack) ----
        const int tn = (kv0 + 32 < hikv) ? t + 1 : t;
#pragma unroll
        for (int ks = 0; ks < 8; ++ks)
            kf[ks] = ld8(ktbase + ((size_t)(tn * 8 + ks) << 9));

        // ---- causal mask: only the diagonal tile ----
        if (kv0 == q0) {
#pragma unroll
            for (int r = 0; r < 16; ++r) {
                const int kvloc = (r & 3) + 8 * (r >> 2) + 4 * hih;
                if (kvloc > l31) sc[r] = -3.0e38f;
            }
        }
        // ---- lane-local max (tree) + cross-half ----
        float t8[8];
#pragma unroll
        for (int i = 0; i < 8; ++i) t8[i] = fmaxf(sc[i], sc[i + 8]);
        float t4a = fmaxf(t8[0], t8[4]), t4b = fmaxf(t8[1], t8[5]);
        float t4c = fmaxf(t8[2], t8[6]), t4d = fmaxf(t8[3], t8[7]);
        float pmax = fmaxf(fmaxf(t4a, t4b), fmaxf(t4c, t4d));
        pmax = fmaxf(pmax, __shfl_xor(pmax, 32));
        // ---- deferred rescale (T13, THR=8) ----
        if (__any(pmax > m_r + 8.f)) {
            const float mn  = fmaxf(m_r, pmax);
            const float fac = __expf(m_r - mn);
            m_r = mn; l_r *= fac;
#pragma unroll
            for (int db = 0; db < 4; ++db)
#pragma unroll
                for (int i = 0; i < 16; ++i) acco[db][i] *= fac;
        }
        // ---- p = exp(s - m), lane-local sum ----
        float p[16];
#pragma unroll
        for (int r = 0; r < 16; ++r) p[r] = __expf(sc[r] - m_r);
        float s8[8];
#pragma unroll
        for (int i = 0; i < 8; ++i) s8[i] = p[i] + p[i + 8];
        float s4a = s8[0] + s8[4], s4b = s8[1] + s8[5];
        float s4c = s8[2] + s8[6], s4d = s8[3] + s8[7];
        float ps = (s4a + s4b) + (s4c + s4d);
        ps += __shfl_xor(ps, 32);
        l_r += ps;
        // ---- pack P^T B-fragments (T12: cvt_pk + permlane32_swap) ----
        u32 pk0 = cvtpk_bf16(p[0], p[1]),   pk2 = cvtpk_bf16(p[4], p[5]);
        swap_halves(pk0, pk2);
        u32 pk1 = cvtpk_bf16(p[2], p[3]),   pk3 = cvtpk_bf16(p[6], p[7]);
        swap_halves(pk1, pk3);
        u32 pk4 = cvtpk_bf16(p[8], p[9]),   pk6 = cvtpk_bf16(p[12], p[13]);
        swap_halves(pk4, pk6);
        u32 pk5 = cvtpk_bf16(p[10], p[11]), pk7 = cvtpk_bf16(p[14], p[15]);
        swap_halves(pk5, pk7);
        union { u32 u[4]; short8 s8v; } ua, ub;
        ua.u[0] = pk0; ua.u[1] = pk1; ua.u[2] = pk2; ua.u[3] = pk3;
        ub.u[0] = pk4; ub.u[1] = pk5; ub.u[2] = pk6; ub.u[3] = pk7;
        const short8 pa0 = ua.s8v, pa1 = ub.s8v;
        // ---- PV: O^T[d][q] += V^T x P^T (vf already in registers) ----
        __builtin_amdgcn_s_setprio(1);
#pragma unroll
        for (int db = 0; db < 4; ++db) {
            acco[db] = __builtin_amdgcn_mfma_f32_32x32x16_bf16(vf[2 * db],     pa0, acco[db], 0, 0, 0);
            acco[db] = __builtin_amdgcn_mfma_f32_32x32x16_bf16(vf[2 * db + 1], pa1, acco[db], 0, 0, 0);
        }
        __builtin_amdgcn_s_setprio(0);
    }

    // ---- write partials (bf16, transposed, coalesced over q) ----
    unsigned short* pt = pacc + (size_t)(s * T32 + t32) * 128 * 32;
#pragma unroll
    for (int db = 0; db < 4; ++db)
#pragma unroll
        for (int r = 0; r < 16; ++r) {
            const int dloc = db * 32 + (r & 3) + 8 * (r >> 2) + 4 * hih;
            pt[(size_t)dloc * 32 + l31] = (unsigned short)f2bf(acco[db][r]);
        }
    if (lane < 32) { pm[mlbase + l31] = m_r; pl[mlbase + l31] = l_r; }
}

// ---------------------------------------------------------------------------
// Combine NS bf16 partials per 32-row tile; LDS transpose for coalesced output.
// ---------------------------------------------------------------------------
__global__ __launch_bounds__(256) void combine_kernel(
    const unsigned short* __restrict__ pacc, const float* __restrict__ pm,
    const float* __restrict__ pl, float* __restrict__ out)
{
    __shared__ float wlds[NS][32];
    __shared__ float tlds[128][33];
    const int t32 = blockIdx.x;
    const int tid = threadIdx.x;

    if (tid < 32) {
        const int q = tid;
        float ms[NS], ls[NS];
        float M = -3.0e38f;
#pragma unroll
        for (int s = 0; s < NS; ++s) {
            ms[s] = pm[(size_t)(s * T32 + t32) * 32 + q];
            ls[s] = pl[(size_t)(s * T32 + t32) * 32 + q];
            M = fmaxf(M, ms[s]);
        }
        float w[NS], den = 0.f;
#pragma unroll
        for (int s = 0; s < NS; ++s) { w[s] = __expf(ms[s] - M); den += w[s] * ls[s]; }
        const float inv = 1.f / den;
#pragma unroll
        for (int s = 0; s < NS; ++s) wlds[s][q] = w[s] * inv;
    }
    __syncthreads();

#pragma unroll
    for (int rep = 0; rep < 16; ++rep) {
        const int flat = rep * 256 + tid;
        const int d = flat >> 5, q = flat & 31;
        float acc = 0.f;
#pragma unroll
        for (int s = 0; s < NS; ++s)
            acc += wlds[s][q] *
                   bf2f(pacc[((size_t)(s * T32 + t32) * 128 + d) * 32 + q]);
        tlds[d][q] = acc;
    }
    __syncthreads();

    const size_t row0 = (size_t)t32 * 32;
#pragma unroll
    for (int rep = 0; rep < 16; ++rep) {
        const int flat = rep * 256 + tid;
        const int q = flat >> 7, d = flat & 127;
        out[(row0 + q) * 128 + d] = tlds[d][q];
    }
}

// ---------------------------------------------------------------------------
extern "C" void kernel_launch(void* const* d_in, const int* in_sizes, int n_in,
                              void* d_out, int out_size, void* d_ws, size_t ws_size,
                              hipStream_t stream)
{
    const float* x  = (const float*)d_in[0];
    const float* Wq = (const float*)d_in[1];
    const float* Wk = (const float*)d_in[2];
    const float* Wv = (const float*)d_in[3];
    float* out = (float*)d_out;

    const size_t TBUF = (size_t)BATCH * NT32 * 8 * 512;           // 2M shorts = 4MB

    unsigned short* wbf  = (unsigned short*)d_ws;                 // 384*1024 bf16
    unsigned short* qt   = wbf + (size_t)384 * DMODEL;
    unsigned short* ktb  = qt + TBUF;
    unsigned short* vtl  = ktb + TBUF;
    unsigned short* pacc = vtl + TBUF;                            // NS*512*128*32 bf16 = 16MB
    float* pm = (float*)(pacc + (size_t)NS * T32 * 128 * 32);
    float* pl = pm + (size_t)NS * T32 * 32;
    // total ~29.3 MB

    const int n8w3 = 3 * HDIM * DMODEL / 8;
    cvt_w_kernel<<<(n8w3 + 255) / 256, 256, 0, stream>>>(Wq, Wk, Wv, wbf);

    qkv_kernel<<<(MROWS / BM) * (384 / BN), 256, 0, stream>>>(x, wbf, qt, ktb, vtl);

    attn_kernel<<<T32 * NS, 64, 0, stream>>>(qt, ktb, vtl, pacc, pm, pl);

    combine_kernel<<<T32, 256, 0, stream>>>(pacc, pm, pl, out);
}

// Round 22
// 79.083 us; speedup vs baseline: 1.3874x; 1.0073x over previous
//
#include <hip/hip_runtime.h>
#include <hip/hip_bf16.h>

#define BATCH  4
#define SEQ    4096
#define DMODEL 1024
#define HDIM   128
#define MROWS  (BATCH * SEQ)   // 16384
#define NT32   (SEQ / 32)      // 128 q-tiles (32 rows) per batch
#define T32    (BATCH * NT32)  // 512
#define NS     4               // KV splits per q-tile (bf16 partials)

// qkv GEMM tile
#define BM 64
#define BN 96
#define BK 64
#define KT (DMODEL / BK)       // 16

typedef __attribute__((ext_vector_type(8)))  short short8;
typedef __attribute__((ext_vector_type(4)))  float floatx4;
typedef __attribute__((ext_vector_type(16))) float floatx16;
typedef unsigned int u32;

static __device__ __forceinline__ short f2bf(float f) {
    __hip_bfloat16 h = __float2bfloat16(f);
    union { __hip_bfloat16 h; short s; } u; u.h = h;
    return u.s;
}

static __device__ __forceinline__ float bf2f(unsigned short s) {
    union { u32 u; float f; } v; v.u = ((u32)s) << 16;
    return v.f;
}

static __device__ __forceinline__ short8 ld8(const unsigned short* p) {
    return *reinterpret_cast<const short8*>(p);
}

// pack two f32 -> one u32 of two bf16 (lo = a, hi = b)
static __device__ __forceinline__ u32 cvtpk_bf16(float a, float b) {
    u32 r;
    asm("v_cvt_pk_bf16_f32 %0, %1, %2" : "=v"(r) : "v"(a), "v"(b));
    return r;
}

// a' = {lanes<32: a ; lanes>=32: b from partner(lane-32)}
// b' = {lanes<32: a from partner(lane+32) ; lanes>=32: b}
static __device__ __forceinline__ void swap_halves(u32& a, u32& b) {
#if __has_builtin(__builtin_amdgcn_permlane32_swap)
    typedef __attribute__((ext_vector_type(2))) int int2v;
    int2v r = __builtin_amdgcn_permlane32_swap((int)a, (int)b, false, false);
    a = (u32)r[0]; b = (u32)r[1];
#else
    u32 ap = (u32)__shfl_xor((int)a, 32);
    u32 bp = (u32)__shfl_xor((int)b, 32);
    const bool hih = (threadIdx.x & 32) != 0;
    u32 na = hih ? bp : a;
    u32 nb = hih ? b : ap;
    a = na; b = nb;
#endif
}

// ===========================================================================
// FRAGMENT-TILED LAYOUTS:
//  qt/kt: (b,s,d) at ((b*NT32+s/32)*8 + d/16)*512 + ((d/8)%2*32 + s%32)*8 + d%8
//  vtl:   (b,s,d) at ((b*NT32+s/32)*8 + (d/32)*2 + (s%32)/16)*512
//                     + ((s/8)%2*32 + d%32)*8 + s%8
//  wbt (NEW, B-fragment tiles of W=[Wq;Wk;Wv]): element (n,k) at
//     ((n/16)*32 + k/32)*512 + ((n%16) + ((k/8)%4)*16)*8 + k%8
//  -> qkv's B loads are per-lane 1KB-coalesced; no B LDS, no gload drain.
// ===========================================================================

// ---------------------------------------------------------------------------
// W = [Wq;Wk;Wv] fp32 -> bf16 B-fragment-tiled, Wq pre-scaled by 1/sqrt(H).
// Thread i handles one k-octet of one W row -> one contiguous short8 store.
// ---------------------------------------------------------------------------
__global__ __launch_bounds__(256) void cvt_w_kernel(
    const float* __restrict__ Wq, const float* __restrict__ Wk,
    const float* __restrict__ Wv, unsigned short* __restrict__ wbt)
{
    const int n8w = HDIM * DMODEL / 8;                // 16384 octets per W
    int i = blockIdx.x * 256 + threadIdx.x;
    if (i >= 3 * n8w) return;
    const int which = i / n8w;
    const int j = i - which * n8w;
    const float* src = (which == 0) ? Wq : (which == 1) ? Wk : Wv;
    const float scale = (which == 0) ? 0.08838834764831845f : 1.0f;
    const float4* s4 = reinterpret_cast<const float4*>(src);
    float4 a = s4[2 * j];
    float4 b = s4[2 * j + 1];
    short8 o;
    o[0] = f2bf(a.x * scale); o[1] = f2bf(a.y * scale);
    o[2] = f2bf(a.z * scale); o[3] = f2bf(a.w * scale);
    o[4] = f2bf(b.x * scale); o[5] = f2bf(b.y * scale);
    o[6] = f2bf(b.z * scale); o[7] = f2bf(b.w * scale);
    const int n  = which * HDIM + (j >> 7);     // global W row 0..383
    const int k0 = (j & 127) * 8;               // k-octet base
    const size_t addr =
        ((size_t)((n >> 4) * 32 + (k0 >> 5)) << 9)
        + (((n & 15) + (((k0 >> 3) & 3) * 16)) * 8);
    *reinterpret_cast<short8*>(wbt + addr) = o;
}

// ---------------------------------------------------------------------------
// QKV projection. y = x @ W^T. BM=64 x BN=96 x BK=64, 1024 blocks.
// A: fp32 reg-staged one tile ahead, cvt, XOR-swizzled ds_write (R12 proven).
// B: NEW — per-lane 1KB-coalesced fragment loads direct from L2-resident
//    tiled wbt (no B LDS, no gload_lds). The per-tile barrier now only
//    orders A's LDS traffic; the vmcnt drain is trivial. LDS 40->16 KB.
// ---------------------------------------------------------------------------
__global__ __launch_bounds__(256, 4) void qkv_kernel(
    const float* __restrict__ x,             // [MROWS][DMODEL] fp32
    const unsigned short* __restrict__ wbt,  // B-fragment-tiled W
    unsigned short* __restrict__ qt,         // tiled Q
    unsigned short* __restrict__ kt,         // tiled K
    unsigned short* __restrict__ vtl)        // tiled V
{
    __shared__ __align__(16) unsigned short A_lds[2][BM][BK];  // 16 KB

    const int raw  = blockIdx.x;
    const int vid  = (raw & 7) * 128 + (raw >> 3);
    const int mblk = vid >> 2;
    const int nblk = vid & 3;
    const int m0   = mblk * BM;
    const int n0   = nblk * BN;
    const int nb0  = n0 >> 4;                 // base ntile (6 per nblk)

    const int tid  = threadIdx.x;
    const int wv   = tid >> 6;
    const int lane = tid & 63;
    const int lr   = lane & 15;
    const int lh   = lane >> 4;
    const int wm   = wv >> 1;   // 0/1 -> M offset 0/32
    const int wn   = wv & 1;    // 0/1 -> N offset 0/48

    const int ar = tid >> 2;
    const int aq = tid & 3;
    const float* asrc = x + (size_t)(m0 + ar) * DMODEL + aq * 16;

    floatx4 acc[2][3];
#pragma unroll
    for (int mf = 0; mf < 2; ++mf)
#pragma unroll
        for (int nf = 0; nf < 3; ++nf) acc[mf][nf] = (floatx4){0.f, 0.f, 0.f, 0.f};

    // ---- prologue: stage A tile 0 into buffer 0 ----
    {
        float4 f0 = *reinterpret_cast<const float4*>(asrc);
        float4 f1 = *reinterpret_cast<const float4*>(asrc + 4);
        float4 f2 = *reinterpret_cast<const float4*>(asrc + 8);
        float4 f3 = *reinterpret_cast<const float4*>(asrc + 12);
        short8 v0, v1;
        v0[0] = f2bf(f0.x); v0[1] = f2bf(f0.y); v0[2] = f2bf(f0.z); v0[3] = f2bf(f0.w);
        v0[4] = f2bf(f1.x); v0[5] = f2bf(f1.y); v0[6] = f2bf(f1.z); v0[7] = f2bf(f1.w);
        v1[0] = f2bf(f2.x); v1[1] = f2bf(f2.y); v1[2] = f2bf(f2.z); v1[3] = f2bf(f2.w);
        v1[4] = f2bf(f3.x); v1[5] = f2bf(f3.y); v1[6] = f2bf(f3.z); v1[7] = f2bf(f3.w);
        const int u0 = (2 * aq)     ^ (ar & 7);
        const int u1 = (2 * aq + 1) ^ (ar & 7);
        *reinterpret_cast<short8*>(&A_lds[0][ar][u0 * 8]) = v0;
        *reinterpret_cast<short8*>(&A_lds[0][ar][u1 * 8]) = v1;
    }
    __syncthreads();

    for (int ktile = 0; ktile < KT; ++ktile) {
        const int cur = ktile & 1;
        const int nxt = cur ^ 1;
        float4 f0, f1, f2, f3;
        if (ktile + 1 < KT) {
            const float* a = asrc + (ktile + 1) * BK;
            f0 = *reinterpret_cast<const float4*>(a);
            f1 = *reinterpret_cast<const float4*>(a + 4);
            f2 = *reinterpret_cast<const float4*>(a + 8);
            f3 = *reinterpret_cast<const float4*>(a + 12);
        }
        // ---- compute: 2 k-steps; B fragments direct from tiled wbt ----
#pragma unroll
        for (int kk = 0; kk < 2; ++kk) {
            const int uswz   = (kk * 4 + lh) ^ (lr & 7);
            const int kchunk = ktile * 2 + kk;
            short8 af[2], bfr[3];
#pragma unroll
            for (int mf = 0; mf < 2; ++mf)
                af[mf] = ld8(&A_lds[cur][wm * 32 + mf * 16 + lr][uswz * 8]);
#pragma unroll
            for (int nf = 0; nf < 3; ++nf)
                bfr[nf] = ld8(wbt
                    + ((size_t)((nb0 + wn * 3 + nf) * 32 + kchunk) << 9)
                    + lane * 8);
#pragma unroll
            for (int mf = 0; mf < 2; ++mf)
#pragma unroll
                for (int nf = 0; nf < 3; ++nf)
                    acc[mf][nf] = __builtin_amdgcn_mfma_f32_16x16x32_bf16(
                        af[mf], bfr[nf], acc[mf][nf], 0, 0, 0);
        }
        if (ktile + 1 < KT) {
            short8 v0, v1;
            v0[0] = f2bf(f0.x); v0[1] = f2bf(f0.y); v0[2] = f2bf(f0.z); v0[3] = f2bf(f0.w);
            v0[4] = f2bf(f1.x); v0[5] = f2bf(f1.y); v0[6] = f2bf(f1.z); v0[7] = f2bf(f1.w);
            v1[0] = f2bf(f2.x); v1[1] = f2bf(f2.y); v1[2] = f2bf(f2.z); v1[3] = f2bf(f2.w);
            v1[4] = f2bf(f3.x); v1[5] = f2bf(f3.y); v1[6] = f2bf(f3.z); v1[7] = f2bf(f3.w);
            const int u0 = (2 * aq)     ^ (ar & 7);
            const int u1 = (2 * aq + 1) ^ (ar & 7);
            *reinterpret_cast<short8*>(&A_lds[nxt][ar][u0 * 8]) = v0;
            *reinterpret_cast<short8*>(&A_lds[nxt][ar][u1 * 8]) = v1;
        }
        __syncthreads();
    }

    // ======== epilogue: LDS-staged, coalesced copy-out (round-16 proven) ====
    __syncthreads();
    unsigned short* out_l = &A_lds[0][0][0];   // 12KB image (16KB avail)

    const int t0 = (m0 & (SEQ - 1)) >> 5;
    const int bb = m0 >> 12;
    const int st = wm;

#pragma unroll
    for (int nf = 0; nf < 3; ++nf) {
        const int cl = wn * 48 + nf * 16 + lr;
#pragma unroll
        for (int mf = 0; mf < 2; ++mf) {
#pragma unroll
            for (int r = 0; r < 4; ++r) {
                const int srow = mf * 16 + lh * 4 + r;
                const unsigned short vv = (unsigned short)f2bf(acc[mf][nf][r]);
                int lf, off;
                if (nblk == 0) {
                    lf  = st * 6 + (cl >> 4);
                    off = ((cl >> 3) & 1) * 256 + srow * 8 + (cl & 7);
                } else if (nblk == 1) {
                    lf  = (cl < 32) ? st * 6 + (cl >> 4)
                                    : st * 6 + 2 + ((cl - 32) >> 4);
                    off = ((cl >> 3) & 1) * 256 + srow * 8 + (cl & 7);
                } else if (nblk == 2) {
                    if (cl < 64) {
                        lf  = st * 6 + (cl >> 4);
                        off = ((cl >> 3) & 1) * 256 + srow * 8 + (cl & 7);
                    } else {
                        const int dg = cl - 64;
                        lf  = st * 6 + 4 + ((srow >> 4) & 1);
                        off = ((srow >> 3) & 1) * 256 + dg * 8 + (srow & 7);
                    }
                } else {
                    const int d = cl + 32;
                    lf  = st * 6 + ((d >> 5) - 1) * 2 + ((srow >> 4) & 1);
                    off = ((srow >> 3) & 1) * 256 + (d & 31) * 8 + (srow & 7);
                }
                out_l[lf * 512 + off] = vv;
            }
        }
    }
    __syncthreads();

#pragma unroll
    for (int k = 0; k < 3; ++k) {
        const int u   = tid + 256 * k;
        const int fb  = u >> 6;
        const int iu  = u & 63;
        const int fst = (fb >= 6) ? 1 : 0;
        const int li  = fb - 6 * fst;
        const size_t tb8 = (size_t)((bb * NT32 + t0 + fst) * 8);
        unsigned short* gbase;
        if (nblk == 0) {
            gbase = qt + ((tb8 + li) << 9);
        } else if (nblk == 1) {
            gbase = (li < 2) ? qt  + ((tb8 + 6 + li) << 9)
                             : kt  + ((tb8 + (li - 2)) << 9);
        } else if (nblk == 2) {
            gbase = (li < 4) ? kt  + ((tb8 + 4 + li) << 9)
                             : vtl + ((tb8 + (li - 4)) << 9);
        } else {
            gbase = vtl + ((tb8 + 2 + li) << 9);
        }
        *reinterpret_cast<short8*>(gbase + iu * 8) =
            *reinterpret_cast<const short8*>(&out_l[fb * 512 + iu * 8]);
    }
}

// ---------------------------------------------------------------------------
// Causal flash attention — round-21 proven (NS=4, K-prefetch, V-early,
// setprio). Unchanged.
// ---------------------------------------------------------------------------
__global__ __launch_bounds__(64) void attn_kernel(
    const unsigned short* __restrict__ qt,
    const unsigned short* __restrict__ kt,
    const unsigned short* __restrict__ vtl,
    unsigned short* __restrict__ pacc,   // [NS][T32][128][32] bf16
    float* __restrict__ pm,
    float* __restrict__ pl)
{
    const int bid  = blockIdx.x;
    const int xcd  = bid & 7;
    const int b    = xcd >> 1;                // batch <-> XCD pair
    const int par  = xcd & 1;
    const int idx  = bid >> 3;                // 0..255 within XCD
    const int s    = idx & 3;                 // split (NS=4)
    const int trk  = idx >> 2;                // 0..63 tile-rank on this XCD
    const int t32b = (NT32 - 1) - (trk * 2 + par);   // longest first
    const int q0   = t32b * 32;
    const int t32  = b * NT32 + t32b;
    const int lane = threadIdx.x & 63;
    const int l31  = lane & 31;
    const int hih  = lane >> 5;

    const int nkv   = q0 + 32;
    const int chunk = ((nkv + NS * 32 - 1) / (NS * 32)) * 32;
    const int lo    = s * chunk;
    const int hikv  = (lo + chunk < nkv) ? lo + chunk : nkv;
    const size_t mlbase = (size_t)(s * T32 + t32) * 32;

    if (lo >= hikv) {
        if (lane < 32) { pm[mlbase + l31] = -3.0e38f; pl[mlbase + l31] = 0.f; }
        return;
    }

    // Q fragments (coalesced tiled loads)
    const unsigned short* qtb =
        qt + ((size_t)((b * NT32 + t32b) * 8) << 9) + lane * 8;
    short8 qa[8];
#pragma unroll
    for (int ks = 0; ks < 8; ++ks) qa[ks] = ld8(qtb + (ks << 9));

    const unsigned short* ktbase = kt  + ((size_t)(b * NT32 * 8) << 9) + lane * 8;
    const unsigned short* vtbase = vtl + ((size_t)(b * NT32 * 8) << 9) + lane * 8;

    floatx16 acco[4];
#pragma unroll
    for (int db = 0; db < 4; ++db)
#pragma unroll
        for (int i = 0; i < 16; ++i) acco[db][i] = 0.f;
    float m_r = -3.0e38f, l_r = 0.f;

    // K pipeline register: preload first tile
    short8 kf[8];
#pragma unroll
    for (int ks = 0; ks < 8; ++ks)
        kf[ks] = ld8(ktbase + ((size_t)((lo >> 5) * 8 + ks) << 9));

    for (int kv0 = lo; kv0 < hikv; kv0 += 32) {
        const int t = kv0 >> 5;
        const unsigned short* vtb = vtbase + ((size_t)(t * 8) << 9);

        // ---- V for current tile: issue early, consumed after softmax ----
        short8 vf[8];
#pragma unroll
        for (int j = 0; j < 8; ++j) vf[j] = ld8(vtb + (j << 9));

        // ---- scores S^T[kv][q] = mfma(K, Q) ----
        floatx16 sc;
#pragma unroll
        for (int i = 0; i < 16; ++i) sc[i] = 0.f;
        __builtin_amdgcn_s_setprio(1);
#pragma unroll
        for (int ks = 0; ks < 8; ++ks)
            sc = __builtin_amdgcn_mfma_f32_32x32x16_bf16(kf[ks], qa[ks], sc, 0, 0, 0);
        __builtin_amdgcn_s_setprio(0);

        // ---- prefetch next K tile (latency hides under softmax/pack) ----
        const int tn = (kv0 + 32 < hikv) ? t + 1 : t;
#pragma unroll
        for (int ks = 0; ks < 8; ++ks)
            kf[ks] = ld8(ktbase + ((size_t)(tn * 8 + ks) << 9));

        // ---- causal mask: only the diagonal tile ----
        if (kv0 == q0) {
#pragma unroll
            for (int r = 0; r < 16; ++r) {
                const int kvloc = (r & 3) + 8 * (r >> 2) + 4 * hih;
                if (kvloc > l31) sc[r] = -3.0e38f;
            }
        }
        // ---- lane-local max (tree) + cross-half ----
        float t8[8];
#pragma unroll
        for (int i = 0; i < 8; ++i) t8[i] = fmaxf(sc[i], sc[i + 8]);
        float t4a = fmaxf(t8[0], t8[4]), t4b = fmaxf(t8[1], t8[5]);
        float t4c = fmaxf(t8[2], t8[6]), t4d = fmaxf(t8[3], t8[7]);
        float pmax = fmaxf(fmaxf(t4a, t4b), fmaxf(t4c, t4d));
        pmax = fmaxf(pmax, __shfl_xor(pmax, 32));
        // ---- deferred rescale (T13, THR=8) ----
        if (__any(pmax > m_r + 8.f)) {
            const float mn  = fmaxf(m_r, pmax);
            const float fac = __expf(m_r - mn);
            m_r = mn; l_r *= fac;
#pragma unroll
            for (int db = 0; db < 4; ++db)
#pragma unroll
                for (int i = 0; i < 16; ++i) acco[db][i] *= fac;
        }
        // ---- p = exp(s - m), lane-local sum ----
        float p[16];
#pragma unroll
        for (int r = 0; r < 16; ++r) p[r] = __expf(sc[r] - m_r);
        float s8[8];
#pragma unroll
        for (int i = 0; i < 8; ++i) s8[i] = p[i] + p[i + 8];
        float s4a = s8[0] + s8[4], s4b = s8[1] + s8[5];
        float s4c = s8[2] + s8[6], s4d = s8[3] + s8[7];
        float ps = (s4a + s4b) + (s4c + s4d);
        ps += __shfl_xor(ps, 32);
        l_r += ps;
        // ---- pack P^T B-fragments (T12: cvt_pk + permlane32_swap) ----
        u32 pk0 = cvtpk_bf16(p[0], p[1]),   pk2 = cvtpk_bf16(p[4], p[5]);
        swap_halves(pk0, pk2);
        u32 pk1 = cvtpk_bf16(p[2], p[3]),   pk3 = cvtpk_bf16(p[6], p[7]);
        swap_halves(pk1, pk3);
        u32 pk4 = cvtpk_bf16(p[8], p[9]),   pk6 = cvtpk_bf16(p[12], p[13]);
        swap_halves(pk4, pk6);
        u32 pk5 = cvtpk_bf16(p[10], p[11]), pk7 = cvtpk_bf16(p[14], p[15]);
        swap_halves(pk5, pk7);
        union { u32 u[4]; short8 s8v; } ua, ub;
        ua.u[0] = pk0; ua.u[1] = pk1; ua.u[2] = pk2; ua.u[3] = pk3;
        ub.u[0] = pk4; ub.u[1] = pk5; ub.u[2] = pk6; ub.u[3] = pk7;
        const short8 pa0 = ua.s8v, pa1 = ub.s8v;
        // ---- PV: O^T[d][q] += V^T x P^T (vf already in registers) ----
        __builtin_amdgcn_s_setprio(1);
#pragma unroll
        for (int db = 0; db < 4; ++db) {
            acco[db] = __builtin_amdgcn_mfma_f32_32x32x16_bf16(vf[2 * db],     pa0, acco[db], 0, 0, 0);
            acco[db] = __builtin_amdgcn_mfma_f32_32x32x16_bf16(vf[2 * db + 1], pa1, acco[db], 0, 0, 0);
        }
        __builtin_amdgcn_s_setprio(0);
    }

    // ---- write partials (bf16, transposed, coalesced over q) ----
    unsigned short* pt = pacc + (size_t)(s * T32 + t32) * 128 * 32;
#pragma unroll
    for (int db = 0; db < 4; ++db)
#pragma unroll
        for (int r = 0; r < 16; ++r) {
            const int dloc = db * 32 + (r & 3) + 8 * (r >> 2) + 4 * hih;
            pt[(size_t)dloc * 32 + l31] = (unsigned short)f2bf(acco[db][r]);
        }
    if (lane < 32) { pm[mlbase + l31] = m_r; pl[mlbase + l31] = l_r; }
}

// ---------------------------------------------------------------------------
// Combine NS bf16 partials per 32-row tile; LDS transpose for coalesced output.
// ---------------------------------------------------------------------------
__global__ __launch_bounds__(256) void combine_kernel(
    const unsigned short* __restrict__ pacc, const float* __restrict__ pm,
    const float* __restrict__ pl, float* __restrict__ out)
{
    __shared__ float wlds[NS][32];
    __shared__ float tlds[128][33];
    const int t32 = blockIdx.x;
    const int tid = threadIdx.x;

    if (tid < 32) {
        const int q = tid;
        float ms[NS], ls[NS];
        float M = -3.0e38f;
#pragma unroll
        for (int s = 0; s < NS; ++s) {
            ms[s] = pm[(size_t)(s * T32 + t32) * 32 + q];
            ls[s] = pl[(size_t)(s * T32 + t32) * 32 + q];
            M = fmaxf(M, ms[s]);
        }
        float w[NS], den = 0.f;
#pragma unroll
        for (int s = 0; s < NS; ++s) { w[s] = __expf(ms[s] - M); den += w[s] * ls[s]; }
        const float inv = 1.f / den;
#pragma unroll
        for (int s = 0; s < NS; ++s) wlds[s][q] = w[s] * inv;
    }
    __syncthreads();

#pragma unroll
    for (int rep = 0; rep < 16; ++rep) {
        const int flat = rep * 256 + tid;
        const int d = flat >> 5, q = flat & 31;
        float acc = 0.f;
#pragma unroll
        for (int s = 0; s < NS; ++s)
            acc += wlds[s][q] *
                   bf2f(pacc[((size_t)(s * T32 + t32) * 128 + d) * 32 + q]);
        tlds[d][q] = acc;
    }
    __syncthreads();

    const size_t row0 = (size_t)t32 * 32;
#pragma unroll
    for (int rep = 0; rep < 16; ++rep) {
        const int flat = rep * 256 + tid;
        const int q = flat >> 7, d = flat & 127;
        out[(row0 + q) * 128 + d] = tlds[d][q];
    }
}

// ---------------------------------------------------------------------------
extern "C" void kernel_launch(void* const* d_in, const int* in_sizes, int n_in,
                              void* d_out, int out_size, void* d_ws, size_t ws_size,
                              hipStream_t stream)
{
    const float* x  = (const float*)d_in[0];
    const float* Wq = (const float*)d_in[1];
    const float* Wk = (const float*)d_in[2];
    const float* Wv = (const float*)d_in[3];
    float* out = (float*)d_out;

    const size_t TBUF = (size_t)BATCH * NT32 * 8 * 512;           // 2M shorts = 4MB

    unsigned short* wbt  = (unsigned short*)d_ws;                 // 384*1024 bf16 (tiled)
    unsigned short* qt   = wbt + (size_t)384 * DMODEL;
    unsigned short* ktb  = qt + TBUF;
    unsigned short* vtl  = ktb + TBUF;
    unsigned short* pacc = vtl + TBUF;                            // NS*512*128*32 bf16 = 16MB
    float* pm = (float*)(pacc + (size_t)NS * T32 * 128 * 32);
    float* pl = pm + (size_t)NS * T32 * 32;
    // total ~29.3 MB

    const int n8w3 = 3 * HDIM * DMODEL / 8;
    cvt_w_kernel<<<(n8w3 + 255) / 256, 256, 0, stream>>>(Wq, Wk, Wv, wbt);

    qkv_kernel<<<(MROWS / BM) * (384 / BN), 256, 0, stream>>>(x, wbt, qt, ktb, vtl);

    attn_kernel<<<T32 * NS, 64, 0, stream>>>(qt, ktb, vtl, pacc, pm, pl);

    combine_kernel<<<T32, 256, 0, stream>>>(pacc, pm, pl, out);
}

// Round 23
// 77.758 us; speedup vs baseline: 1.4111x; 1.0170x over previous
//
#include <hip/hip_runtime.h>
#include <hip/hip_bf16.h>

#define BATCH  4
#define SEQ    4096
#define DMODEL 1024
#define HDIM   128
#define MROWS  (BATCH * SEQ)   // 16384
#define NT32   (SEQ / 32)      // 128 q-tiles (32 rows) per batch
#define T32    (BATCH * NT32)  // 512
#define NS     4               // KV splits per q-tile (bf16 partials)

// qkv GEMM tile
#define BM 64
#define BN 96
#define BK 64
#define KT (DMODEL / BK)       // 16

typedef __attribute__((ext_vector_type(8)))  short short8;
typedef __attribute__((ext_vector_type(4)))  float floatx4;
typedef __attribute__((ext_vector_type(16))) float floatx16;
typedef unsigned int u32;

static __device__ __forceinline__ short f2bf(float f) {
    __hip_bfloat16 h = __float2bfloat16(f);
    union { __hip_bfloat16 h; short s; } u; u.h = h;
    return u.s;
}

static __device__ __forceinline__ float bf2f(unsigned short s) {
    union { u32 u; float f; } v; v.u = ((u32)s) << 16;
    return v.f;
}

static __device__ __forceinline__ short8 ld8(const unsigned short* p) {
    return *reinterpret_cast<const short8*>(p);
}

// pack two f32 -> one u32 of two bf16 (lo = a, hi = b)
static __device__ __forceinline__ u32 cvtpk_bf16(float a, float b) {
    u32 r;
    asm("v_cvt_pk_bf16_f32 %0, %1, %2" : "=v"(r) : "v"(a), "v"(b));
    return r;
}

// a' = {lanes<32: a ; lanes>=32: b from partner(lane-32)}
// b' = {lanes<32: a from partner(lane+32) ; lanes>=32: b}
static __device__ __forceinline__ void swap_halves(u32& a, u32& b) {
#if __has_builtin(__builtin_amdgcn_permlane32_swap)
    typedef __attribute__((ext_vector_type(2))) int int2v;
    int2v r = __builtin_amdgcn_permlane32_swap((int)a, (int)b, false, false);
    a = (u32)r[0]; b = (u32)r[1];
#else
    u32 ap = (u32)__shfl_xor((int)a, 32);
    u32 bp = (u32)__shfl_xor((int)b, 32);
    const bool hih = (threadIdx.x & 32) != 0;
    u32 na = hih ? bp : a;
    u32 nb = hih ? b : ap;
    a = na; b = nb;
#endif
}

// ===========================================================================
// FRAGMENT-TILED LAYOUTS:
//  qt/kt: (b,s,d) at ((b*NT32+s/32)*8 + d/16)*512 + ((d/8)%2*32 + s%32)*8 + d%8
//  vtl:   (b,s,d) at ((b*NT32+s/32)*8 + (d/32)*2 + (s%32)/16)*512
//                     + ((s/8)%2*32 + d%32)*8 + s%8
//  wbt (B-fragment tiles of W=[Wq;Wk;Wv]): element (n,k) at
//     ((n/16)*32 + k/32)*512 + ((n%16) + ((k/8)%4)*16)*8 + k%8
// ===========================================================================

// ---------------------------------------------------------------------------
// W = [Wq;Wk;Wv] fp32 -> bf16 B-fragment-tiled, Wq pre-scaled by 1/sqrt(H).
// ---------------------------------------------------------------------------
__global__ __launch_bounds__(256) void cvt_w_kernel(
    const float* __restrict__ Wq, const float* __restrict__ Wk,
    const float* __restrict__ Wv, unsigned short* __restrict__ wbt)
{
    const int n8w = HDIM * DMODEL / 8;                // 16384 octets per W
    int i = blockIdx.x * 256 + threadIdx.x;
    if (i >= 3 * n8w) return;
    const int which = i / n8w;
    const int j = i - which * n8w;
    const float* src = (which == 0) ? Wq : (which == 1) ? Wk : Wv;
    const float scale = (which == 0) ? 0.08838834764831845f : 1.0f;
    const float4* s4 = reinterpret_cast<const float4*>(src);
    float4 a = s4[2 * j];
    float4 b = s4[2 * j + 1];
    short8 o;
    o[0] = f2bf(a.x * scale); o[1] = f2bf(a.y * scale);
    o[2] = f2bf(a.z * scale); o[3] = f2bf(a.w * scale);
    o[4] = f2bf(b.x * scale); o[5] = f2bf(b.y * scale);
    o[6] = f2bf(b.z * scale); o[7] = f2bf(b.w * scale);
    const int n  = which * HDIM + (j >> 7);     // global W row 0..383
    const int k0 = (j & 127) * 8;               // k-octet base
    const size_t addr =
        ((size_t)((n >> 4) * 32 + (k0 >> 5)) << 9)
        + (((n & 15) + (((k0 >> 3) & 3) * 16)) * 8);
    *reinterpret_cast<short8*>(wbt + addr) = o;
}

// ---------------------------------------------------------------------------
// QKV projection. y = x @ W^T. BM=64 x BN=96 x BK=64, 1024 blocks.
// A: fp32 reg-staged TWO tiles ahead (pfA/pfB named sets, 2-unrolled loop —
//    the ~600-900cy HBM latency of the x load is now covered by ~2 tiles of
//    compute instead of ~1, the invariant serializer in all prior variants).
// B: per-lane 1KB-coalesced fragment loads direct from L2-resident wbt.
// ---------------------------------------------------------------------------
__global__ __launch_bounds__(256, 4) void qkv_kernel(
    const float* __restrict__ x,             // [MROWS][DMODEL] fp32
    const unsigned short* __restrict__ wbt,  // B-fragment-tiled W
    unsigned short* __restrict__ qt,         // tiled Q
    unsigned short* __restrict__ kt,         // tiled K
    unsigned short* __restrict__ vtl)        // tiled V
{
    __shared__ __align__(16) unsigned short A_lds[2][BM][BK];  // 16 KB

    const int raw  = blockIdx.x;
    const int vid  = (raw & 7) * 128 + (raw >> 3);
    const int mblk = vid >> 2;
    const int nblk = vid & 3;
    const int m0   = mblk * BM;
    const int n0   = nblk * BN;
    const int nb0  = n0 >> 4;                 // base ntile

    const int tid  = threadIdx.x;
    const int wv   = tid >> 6;
    const int lane = tid & 63;
    const int lr   = lane & 15;
    const int lh   = lane >> 4;
    const int wm   = wv >> 1;   // 0/1 -> M offset 0/32
    const int wn   = wv & 1;    // 0/1 -> N offset 0/48

    const int ar = tid >> 2;
    const int aq = tid & 3;
    const float* asrc = x + (size_t)(m0 + ar) * DMODEL + aq * 16;
    const int u0 = (2 * aq)     ^ (ar & 7);
    const int u1 = (2 * aq + 1) ^ (ar & 7);

    floatx4 acc[2][3];
#pragma unroll
    for (int mf = 0; mf < 2; ++mf)
#pragma unroll
        for (int nf = 0; nf < 3; ++nf) acc[mf][nf] = (floatx4){0.f, 0.f, 0.f, 0.f};

// compute macro: reads A fragments from LDS[CUR], B direct from wbt
#define QKV_COMPUTE(CUR, KTILE)                                               \
    {                                                                         \
        _Pragma("unroll")                                                     \
        for (int kk = 0; kk < 2; ++kk) {                                      \
            const int uswz   = (kk * 4 + lh) ^ (lr & 7);                      \
            const int kchunk = (KTILE) * 2 + kk;                              \
            short8 af[2], bfr[3];                                             \
            _Pragma("unroll")                                                 \
            for (int mf = 0; mf < 2; ++mf)                                    \
                af[mf] = ld8(&A_lds[CUR][wm * 32 + mf * 16 + lr][uswz * 8]);  \
            _Pragma("unroll")                                                 \
            for (int nf = 0; nf < 3; ++nf)                                    \
                bfr[nf] = ld8(wbt                                             \
                    + ((size_t)((nb0 + wn * 3 + nf) * 32 + kchunk) << 9)      \
                    + lane * 8);                                              \
            _Pragma("unroll")                                                 \
            for (int mf = 0; mf < 2; ++mf)                                    \
                _Pragma("unroll")                                             \
                for (int nf = 0; nf < 3; ++nf)                                \
                    acc[mf][nf] = __builtin_amdgcn_mfma_f32_16x16x32_bf16(    \
                        af[mf], bfr[nf], acc[mf][nf], 0, 0, 0);               \
        }                                                                     \
    }

// cvt 4xfloat4-pair regs -> swizzled LDS[DST] write
#define QKV_WRITE(DST, P0, P1, P2, P3)                                        \
    {                                                                         \
        short8 v0, v1;                                                        \
        v0[0] = f2bf((P0).x); v0[1] = f2bf((P0).y);                           \
        v0[2] = f2bf((P0).z); v0[3] = f2bf((P0).w);                           \
        v0[4] = f2bf((P1).x); v0[5] = f2bf((P1).y);                           \
        v0[6] = f2bf((P1).z); v0[7] = f2bf((P1).w);                           \
        v1[0] = f2bf((P2).x); v1[1] = f2bf((P2).y);                           \
        v1[2] = f2bf((P2).z); v1[3] = f2bf((P2).w);                           \
        v1[4] = f2bf((P3).x); v1[5] = f2bf((P3).y);                           \
        v1[6] = f2bf((P3).z); v1[7] = f2bf((P3).w);                           \
        *reinterpret_cast<short8*>(&A_lds[DST][ar][u0 * 8]) = v0;             \
        *reinterpret_cast<short8*>(&A_lds[DST][ar][u1 * 8]) = v1;             \
    }

#define QKV_LOAD(P0, P1, P2, P3, KTILE)                                       \
    {                                                                         \
        const float* a_ = asrc + (KTILE) * BK;                                \
        P0 = *reinterpret_cast<const float4*>(a_);                            \
        P1 = *reinterpret_cast<const float4*>(a_ + 4);                        \
        P2 = *reinterpret_cast<const float4*>(a_ + 8);                        \
        P3 = *reinterpret_cast<const float4*>(a_ + 12);                       \
    }

    float4 a0, a1, a2, a3;          // pfA set
    float4 b0, b1, b2, b3;          // pfB set

    // ---- prologue: tile 0 sync to LDS[0]; issue A(1)->pfA, A(2)->pfB ----
    {
        float4 f0, f1, f2, f3;
        QKV_LOAD(f0, f1, f2, f3, 0);
        QKV_WRITE(0, f0, f1, f2, f3);
        QKV_LOAD(a0, a1, a2, a3, 1);
        QKV_LOAD(b0, b1, b2, b3, 2);
    }
    __syncthreads();

    for (int ktp = 0; ktp < KT; ktp += 2) {
        // ===== body even: kt = ktp, compute LDS[0] =====
        QKV_COMPUTE(0, ktp);
        // write tile ktp+1 from pfA (ktp+1 <= 15 always)
        QKV_WRITE(1, a0, a1, a2, a3);
        if (ktp + 3 < KT) QKV_LOAD(a0, a1, a2, a3, ktp + 3);
        __syncthreads();
        // ===== body odd: kt = ktp+1, compute LDS[1] =====
        QKV_COMPUTE(1, ktp + 1);
        if (ktp + 2 < KT) {
            QKV_WRITE(0, b0, b1, b2, b3);
            if (ktp + 4 < KT) QKV_LOAD(b0, b1, b2, b3, ktp + 4);
        }
        __syncthreads();
    }

#undef QKV_COMPUTE
#undef QKV_WRITE
#undef QKV_LOAD

    // ======== epilogue: LDS-staged, coalesced copy-out (round-16 proven) ====
    unsigned short* out_l = &A_lds[0][0][0];   // 12KB image (16KB avail)

    const int t0 = (m0 & (SEQ - 1)) >> 5;
    const int bb = m0 >> 12;
    const int st = wm;

#pragma unroll
    for (int nf = 0; nf < 3; ++nf) {
        const int cl = wn * 48 + nf * 16 + lr;
#pragma unroll
        for (int mf = 0; mf < 2; ++mf) {
#pragma unroll
            for (int r = 0; r < 4; ++r) {
                const int srow = mf * 16 + lh * 4 + r;
                const unsigned short vv = (unsigned short)f2bf(acc[mf][nf][r]);
                int lf, off;
                if (nblk == 0) {
                    lf  = st * 6 + (cl >> 4);
                    off = ((cl >> 3) & 1) * 256 + srow * 8 + (cl & 7);
                } else if (nblk == 1) {
                    lf  = (cl < 32) ? st * 6 + (cl >> 4)
                                    : st * 6 + 2 + ((cl - 32) >> 4);
                    off = ((cl >> 3) & 1) * 256 + srow * 8 + (cl & 7);
                } else if (nblk == 2) {
                    if (cl < 64) {
                        lf  = st * 6 + (cl >> 4);
                        off = ((cl >> 3) & 1) * 256 + srow * 8 + (cl & 7);
                    } else {
                        const int dg = cl - 64;
                        lf  = st * 6 + 4 + ((srow >> 4) & 1);
                        off = ((srow >> 3) & 1) * 256 + dg * 8 + (srow & 7);
                    }
                } else {
                    const int d = cl + 32;
                    lf  = st * 6 + ((d >> 5) - 1) * 2 + ((srow >> 4) & 1);
                    off = ((srow >> 3) & 1) * 256 + (d & 31) * 8 + (srow & 7);
                }
                out_l[lf * 512 + off] = vv;
            }
        }
    }
    __syncthreads();

#pragma unroll
    for (int k = 0; k < 3; ++k) {
        const int u   = tid + 256 * k;
        const int fb  = u >> 6;
        const int iu  = u & 63;
        const int fst = (fb >= 6) ? 1 : 0;
        const int li  = fb - 6 * fst;
        const size_t tb8 = (size_t)((bb * NT32 + t0 + fst) * 8);
        unsigned short* gbase;
        if (nblk == 0) {
            gbase = qt + ((tb8 + li) << 9);
        } else if (nblk == 1) {
            gbase = (li < 2) ? qt  + ((tb8 + 6 + li) << 9)
                             : kt  + ((tb8 + (li - 2)) << 9);
        } else if (nblk == 2) {
            gbase = (li < 4) ? kt  + ((tb8 + 4 + li) << 9)
                             : vtl + ((tb8 + (li - 4)) << 9);
        } else {
            gbase = vtl + ((tb8 + 2 + li) << 9);
        }
        *reinterpret_cast<short8*>(gbase + iu * 8) =
            *reinterpret_cast<const short8*>(&out_l[fb * 512 + iu * 8]);
    }
}

// ---------------------------------------------------------------------------
// Causal flash attention — round-21 proven (NS=4, K-prefetch, V-early,
// setprio). Unchanged.
// ---------------------------------------------------------------------------
__global__ __launch_bounds__(64) void attn_kernel(
    const unsigned short* __restrict__ qt,
    const unsigned short* __restrict__ kt,
    const unsigned short* __restrict__ vtl,
    unsigned short* __restrict__ pacc,   // [NS][T32][128][32] bf16
    float* __restrict__ pm,
    float* __restrict__ pl)
{
    const int bid  = blockIdx.x;
    const int xcd  = bid & 7;
    const int b    = xcd >> 1;                // batch <-> XCD pair
    const int par  = xcd & 1;
    const int idx  = bid >> 3;                // 0..255 within XCD
    const int s    = idx & 3;                 // split (NS=4)
    const int trk  = idx >> 2;                // 0..63 tile-rank on this XCD
    const int t32b = (NT32 - 1) - (trk * 2 + par);   // longest first
    const int q0   = t32b * 32;
    const int t32  = b * NT32 + t32b;
    const int lane = threadIdx.x & 63;
    const int l31  = lane & 31;
    const int hih  = lane >> 5;

    const int nkv   = q0 + 32;
    const int chunk = ((nkv + NS * 32 - 1) / (NS * 32)) * 32;
    const int lo    = s * chunk;
    const int hikv  = (lo + chunk < nkv) ? lo + chunk : nkv;
    const size_t mlbase = (size_t)(s * T32 + t32) * 32;

    if (lo >= hikv) {
        if (lane < 32) { pm[mlbase + l31] = -3.0e38f; pl[mlbase + l31] = 0.f; }
        return;
    }

    // Q fragments (coalesced tiled loads)
    const unsigned short* qtb =
        qt + ((size_t)((b * NT32 + t32b) * 8) << 9) + lane * 8;
    short8 qa[8];
#pragma unroll
    for (int ks = 0; ks < 8; ++ks) qa[ks] = ld8(qtb + (ks << 9));

    const unsigned short* ktbase = kt  + ((size_t)(b * NT32 * 8) << 9) + lane * 8;
    const unsigned short* vtbase = vtl + ((size_t)(b * NT32 * 8) << 9) + lane * 8;

    floatx16 acco[4];
#pragma unroll
    for (int db = 0; db < 4; ++db)
#pragma unroll
        for (int i = 0; i < 16; ++i) acco[db][i] = 0.f;
    float m_r = -3.0e38f, l_r = 0.f;

    // K pipeline register: preload first tile
    short8 kf[8];
#pragma unroll
    for (int ks = 0; ks < 8; ++ks)
        kf[ks] = ld8(ktbase + ((size_t)((lo >> 5) * 8 + ks) << 9));

    for (int kv0 = lo; kv0 < hikv; kv0 += 32) {
        const int t = kv0 >> 5;
        const unsigned short* vtb = vtbase + ((size_t)(t * 8) << 9);

        // ---- V for current tile: issue early, consumed after softmax ----
        short8 vf[8];
#pragma unroll
        for (int j = 0; j < 8; ++j) vf[j] = ld8(vtb + (j << 9));

        // ---- scores S^T[kv][q] = mfma(K, Q) ----
        floatx16 sc;
#pragma unroll
        for (int i = 0; i < 16; ++i) sc[i] = 0.f;
        __builtin_amdgcn_s_setprio(1);
#pragma unroll
        for (int ks = 0; ks < 8; ++ks)
            sc = __builtin_amdgcn_mfma_f32_32x32x16_bf16(kf[ks], qa[ks], sc, 0, 0, 0);
        __builtin_amdgcn_s_setprio(0);

        // ---- prefetch next K tile (latency hides under softmax/pack) ----
        const int tn = (kv0 + 32 < hikv) ? t + 1 : t;
#pragma unroll
        for (int ks = 0; ks < 8; ++ks)
            kf[ks] = ld8(ktbase + ((size_t)(tn * 8 + ks) << 9));

        // ---- causal mask: only the diagonal tile ----
        if (kv0 == q0) {
#pragma unroll
            for (int r = 0; r < 16; ++r) {
                const int kvloc = (r & 3) + 8 * (r >> 2) + 4 * hih;
                if (kvloc > l31) sc[r] = -3.0e38f;
            }
        }
        // ---- lane-local max (tree) + cross-half ----
        float t8[8];
#pragma unroll
        for (int i = 0; i < 8; ++i) t8[i] = fmaxf(sc[i], sc[i + 8]);
        float t4a = fmaxf(t8[0], t8[4]), t4b = fmaxf(t8[1], t8[5]);
        float t4c = fmaxf(t8[2], t8[6]), t4d = fmaxf(t8[3], t8[7]);
        float pmax = fmaxf(fmaxf(t4a, t4b), fmaxf(t4c, t4d));
        pmax = fmaxf(pmax, __shfl_xor(pmax, 32));
        // ---- deferred rescale (T13, THR=8) ----
        if (__any(pmax > m_r + 8.f)) {
            const float mn  = fmaxf(m_r, pmax);
            const float fac = __expf(m_r - mn);
            m_r = mn; l_r *= fac;
#pragma unroll
            for (int db = 0; db < 4; ++db)
#pragma unroll
                for (int i = 0; i < 16; ++i) acco[db][i] *= fac;
        }
        // ---- p = exp(s - m), lane-local sum ----
        float p[16];
#pragma unroll
        for (int r = 0; r < 16; ++r) p[r] = __expf(sc[r] - m_r);
        float s8[8];
#pragma unroll
        for (int i = 0; i < 8; ++i) s8[i] = p[i] + p[i + 8];
        float s4a = s8[0] + s8[4], s4b = s8[1] + s8[5];
        float s4c = s8[2] + s8[6], s4d = s8[3] + s8[7];
        float ps = (s4a + s4b) + (s4c + s4d);
        ps += __shfl_xor(ps, 32);
        l_r += ps;
        // ---- pack P^T B-fragments (T12: cvt_pk + permlane32_swap) ----
        u32 pk0 = cvtpk_bf16(p[0], p[1]),   pk2 = cvtpk_bf16(p[4], p[5]);
        swap_halves(pk0, pk2);
        u32 pk1 = cvtpk_bf16(p[2], p[3]),   pk3 = cvtpk_bf16(p[6], p[7]);
        swap_halves(pk1, pk3);
        u32 pk4 = cvtpk_bf16(p[8], p[9]),   pk6 = cvtpk_bf16(p[12], p[13]);
        swap_halves(pk4, pk6);
        u32 pk5 = cvtpk_bf16(p[10], p[11]), pk7 = cvtpk_bf16(p[14], p[15]);
        swap_halves(pk5, pk7);
        union { u32 u[4]; short8 s8v; } ua, ub;
        ua.u[0] = pk0; ua.u[1] = pk1; ua.u[2] = pk2; ua.u[3] = pk3;
        ub.u[0] = pk4; ub.u[1] = pk5; ub.u[2] = pk6; ub.u[3] = pk7;
        const short8 pa0 = ua.s8v, pa1 = ub.s8v;
        // ---- PV: O^T[d][q] += V^T x P^T (vf already in registers) ----
        __builtin_amdgcn_s_setprio(1);
#pragma unroll
        for (int db = 0; db < 4; ++db) {
            acco[db] = __builtin_amdgcn_mfma_f32_32x32x16_bf16(vf[2 * db],     pa0, acco[db], 0, 0, 0);
            acco[db] = __builtin_amdgcn_mfma_f32_32x32x16_bf16(vf[2 * db + 1], pa1, acco[db], 0, 0, 0);
        }
        __builtin_amdgcn_s_setprio(0);
    }

    // ---- write partials (bf16, transposed, coalesced over q) ----
    unsigned short* pt = pacc + (size_t)(s * T32 + t32) * 128 * 32;
#pragma unroll
    for (int db = 0; db < 4; ++db)
#pragma unroll
        for (int r = 0; r < 16; ++r) {
            const int dloc = db * 32 + (r & 3) + 8 * (r >> 2) + 4 * hih;
            pt[(size_t)dloc * 32 + l31] = (unsigned short)f2bf(acco[db][r]);
        }
    if (lane < 32) { pm[mlbase + l31] = m_r; pl[mlbase + l31] = l_r; }
}

// ---------------------------------------------------------------------------
// Combine NS bf16 partials per 32-row tile; LDS transpose for coalesced output.
// ---------------------------------------------------------------------------
__global__ __launch_bounds__(256) void combine_kernel(
    const unsigned short* __restrict__ pacc, const float* __restrict__ pm,
    const float* __restrict__ pl, float* __restrict__ out)
{
    __shared__ float wlds[NS][32];
    __shared__ float tlds[128][33];
    const int t32 = blockIdx.x;
    const int tid = threadIdx.x;

    if (tid < 32) {
        const int q = tid;
        float ms[NS], ls[NS];
        float M = -3.0e38f;
#pragma unroll
        for (int s = 0; s < NS; ++s) {
            ms[s] = pm[(size_t)(s * T32 + t32) * 32 + q];
            ls[s] = pl[(size_t)(s * T32 + t32) * 32 + q];
            M = fmaxf(M, ms[s]);
        }
        float w[NS], den = 0.f;
#pragma unroll
        for (int s = 0; s < NS; ++s) { w[s] = __expf(ms[s] - M); den += w[s] * ls[s]; }
        const float inv = 1.f / den;
#pragma unroll
        for (int s = 0; s < NS; ++s) wlds[s][q] = w[s] * inv;
    }
    __syncthreads();

#pragma unroll
    for (int rep = 0; rep < 16; ++rep) {
        const int flat = rep * 256 + tid;
        const int d = flat >> 5, q = flat & 31;
        float acc = 0.f;
#pragma unroll
        for (int s = 0; s < NS; ++s)
            acc += wlds[s][q] *
                   bf2f(pacc[((size_t)(s * T32 + t32) * 128 + d) * 32 + q]);
        tlds[d][q] = acc;
    }
    __syncthreads();

    const size_t row0 = (size_t)t32 * 32;
#pragma unroll
    for (int rep = 0; rep < 16; ++rep) {
        const int flat = rep * 256 + tid;
        const int q = flat >> 7, d = flat & 127;
        out[(row0 + q) * 128 + d] = tlds[d][q];
    }
}

// ---------------------------------------------------------------------------
extern "C" void kernel_launch(void* const* d_in, const int* in_sizes, int n_in,
                              void* d_out, int out_size, void* d_ws, size_t ws_size,
                              hipStream_t stream)
{
    const float* x  = (const float*)d_in[0];
    const float* Wq = (const float*)d_in[1];
    const float* Wk = (const float*)d_in[2];
    const float* Wv = (const float*)d_in[3];
    float* out = (float*)d_out;

    const size_t TBUF = (size_t)BATCH * NT32 * 8 * 512;           // 2M shorts = 4MB

    unsigned short* wbt  = (unsigned short*)d_ws;                 // 384*1024 bf16 (tiled)
    unsigned short* qt   = wbt + (size_t)384 * DMODEL;
    unsigned short* ktb  = qt + TBUF;
    unsigned short* vtl  = ktb + TBUF;
    unsigned short* pacc = vtl + TBUF;                            // NS*512*128*32 bf16 = 16MB
    float* pm = (float*)(pacc + (size_t)NS * T32 * 128 * 32);
    float* pl = pm + (size_t)NS * T32 * 32;
    // total ~29.3 MB

    const int n8w3 = 3 * HDIM * DMODEL / 8;
    cvt_w_kernel<<<(n8w3 + 255) / 256, 256, 0, stream>>>(Wq, Wk, Wv, wbt);

    qkv_kernel<<<(MROWS / BM) * (384 / BN), 256, 0, stream>>>(x, wbt, qt, ktb, vtl);

    attn_kernel<<<T32 * NS, 64, 0, stream>>>(qt, ktb, vtl, pacc, pm, pl);

    combine_kernel<<<T32, 256, 0, stream>>>(pacc, pm, pl, out);
}